// Round 5
// baseline (716.061 us; speedup 1.0000x reference)
//
#include <hip/hip_runtime.h>
#include <hip/hip_cooperative_groups.h>
#include <stdint.h>
#include <string.h>

namespace cg = cooperative_groups;

typedef unsigned int u32;
typedef unsigned long long u64;

#define B_ 8
#define N_ 100000
#define C_ 10
#define K1_ 1000
#define N2_ (C_ * K1_)
#define NBIN 4096
#define CAP 4096       // fallback / topk2 sort capacity
#define CAP_C 2048     // fast-path candidate capacity per slice
#define SEGROWS 256    // fused-NMS segment rows (fallback path)
#define MIN_CONF_F 0.05f
#define NMS_IOU_F 0.4f
#define POST_IOU_F 0.65f
#define T0_F 0.985f    // conservative fast-path threshold (per-slice count ~1500)

#define TOTAL_F4 (B_ * N_ * C_ / 4)  // 2,000,000 float4s
#define CBLK 512                     // compact chunks
#define LCAP 512                     // per-chunk candidate capacity (lambda~234, 18 sigma)
#define HDRW 84                      // u32 stride per compact-chunk header

// split-NMS parameters
#define NTILE 136   // upper-triangular 64x64 tiles of the 1024x1024 pair matrix
#define NB_ 34      // classic build blocks per slice (4 waves each -> 1 tile per wave)
#define TPB_ 4      // classic tiles per build block
#define NBLK_ 240   // cooperative mega-kernel grid (1 block/CU co-resident)

static __device__ __forceinline__ u32 next_pow2_ge(u32 x, u32 lo, u32 hi) {
  u32 n = lo;
  while (n < x && n < hi) n <<= 1;
  return n;
}

// triangular tile id of (rt, w), w >= rt
#define TILE_ID(rt, w) ((rt) * 16 - (((rt) * ((rt) - 1)) >> 1) + ((w) - (rt)))

// Prep: one thread writes one corner record (bit-identical FP to the
// validated k_nms_prep body).
static __device__ __forceinline__ void prep_write(const float* __restrict__ bb,
                                                  float s, int oi,
                                                  float4* __restrict__ cor,
                                                  int pos) {
  bool v = (s >= MIN_CONF_F);
  float cx = 0.f, cy = 0.f, w = 0.f, h = 0.f;
  if (v) {
    const float4 bp = *(const float4*)(bb + (size_t)oi * 4);
    cx = bp.x; cy = bp.y; w = bp.z; h = bp.w;
  }
  float y1 = cy - h * 0.5f, x1 = cx - w * 0.5f;
  float y2 = cy + h * 0.5f, x2 = cx + w * 0.5f;
  cor[pos] = make_float4(y1, x1, y2, x2);
}

// Exact threshold predicate, all-f32 (double-float). Reproduces
// (double)inter OP M*(double)den where M = m1+m0 (25-bit midpoint, product
// exact in f64): t+e = m1*den exactly (TwoProdFMA), r = fl(e + m0*den) —
// single rounding preserves sign incl. exact ties; d = inter-t is exact in
// the decision region (Sterbenz). _rn intrinsics pin against fp-contract.
template <bool STRICT>
static __device__ __forceinline__ bool iou_pred(float inter, float den,
                                                float m1, float m0) {
  float t = __fmul_rn(m1, den);
  float e = __builtin_fmaf(m1, den, -t);
  float r = __builtin_fmaf(m0, den, e);
  float d = __fsub_rn(inter, t);
  return STRICT ? (d > r) : (d >= r);
}

// One 64x64 mask tile from LDS-resident corners/areas (validated R14 body).
template <bool STRICT>
static __device__ __forceinline__ void build_tile(const float4* __restrict__ box4,
                                                  const float* __restrict__ area,
                                                  int tt, int lane,
                                                  float m1, float m0,
                                                  u64* __restrict__ mg) {
  int rt = 0, bse = 0;
  while (tt >= bse + (16 - rt)) { bse += 16 - rt; ++rt; }
  const int w = rt + (tt - bse);
  const int row = (rt << 6) | lane;

  const float4 ib = box4[row];
  const float ia = area[row];
  const float4* jcol = &box4[w << 6];
  const float* jarea = &area[w << 6];
  u32 mhi = 0, mlo = 0;
#pragma unroll 8
  for (int j = 63; j >= 32; --j) {
    const float4 jb = jcol[j];
    const float ja = jarea[j];
    float ih = fminf(ib.z, jb.z) - fmaxf(ib.x, jb.x); ih = fmaxf(ih, 0.0f);
    float iw_ = fminf(ib.w, jb.w) - fmaxf(ib.y, jb.y); iw_ = fmaxf(iw_, 0.0f);
    float inter = ih * iw_;
    float den = fmaxf((ia + ja) - inter, 1e-8f);
    bool p_ = iou_pred<STRICT>(inter, den, m1, m0);
    mhi = (mhi << 1) | (p_ ? 1u : 0u);
  }
#pragma unroll 8
  for (int j = 31; j >= 0; --j) {
    const float4 jb = jcol[j];
    const float ja = jarea[j];
    float ih = fminf(ib.z, jb.z) - fmaxf(ib.x, jb.x); ih = fmaxf(ih, 0.0f);
    float iw_ = fminf(ib.w, jb.w) - fmaxf(ib.y, jb.y); iw_ = fmaxf(iw_, 0.0f);
    float inter = ih * iw_;
    float den = fmaxf((ia + ja) - inter, 1e-8f);
    bool p_ = iou_pred<STRICT>(inter, den, m1, m0);
    mlo = (mlo << 1) | (p_ ? 1u : 0u);
  }
  u64 m = ((u64)mhi << 32) | (u64)mlo;
  if (w == rt) m &= (lane == 63) ? 0ull : (~0ull << (lane + 1));
  mg[(tt << 6) + lane] = m;  // coalesced 512-B store
}

// ---------------------------------------------------------------------------
// Bitonic sort for 1024 threads: one exchange per thread per step.
// ---------------------------------------------------------------------------
__device__ __forceinline__ void bitonic_sort_desc(u64* buf, u32 n, int tid,
                                                  int bd) {
  for (u32 kk = 2; kk <= n; kk <<= 1) {
    for (u32 j = kk >> 1; j > 0; j >>= 1) {
      for (u32 t = tid; t < (n >> 1); t += bd) {
        u32 i = ((t & ~(j - 1)) << 1) | (t & (j - 1));
        u32 l = i | j;
        u64 a = buf[i], bb = buf[l];
        bool desc = ((i & kk) == 0);
        if (desc ? (a < bb) : (a > bb)) { buf[i] = bb; buf[l] = a; }
      }
      __syncthreads();
    }
  }
}

// Hierarchical scan core (rolled, O(1) registers). Greedy visits ONLY rows
// with nonzero suppression masks (nz ballot): exact greedy keep set.
// s = this thread's row score (valid iff >= MIN_CONF).
__device__ void scan_core(const u64* __restrict__ mg, float s,
                          u64* __restrict__ keepb) {
  const int tid = threadIdx.x, wv = tid >> 6, lane = tid & 63;
  const u64 myvalid = __ballot(s >= MIN_CONF_F);

  u64 ext_partial = 0;

#pragma unroll 1
  for (int g = 0; g < 16; ++g) {
    u64 Tg = 0ull;
    if (g <= wv) Tg = mg[(TILE_ID(g, wv) << 6) + lane];
    const u64 nz = __ballot(Tg != 0ull);  // suppressor rows in this tile
    if (wv == g) {
      u64 ext = ext_partial;
      for (int off = 1; off < 64; off <<= 1) {
        u32 lo = (u32)__shfl_xor((int)(u32)ext, off, 64);
        u32 hi = (u32)__shfl_xor((int)(u32)(ext >> 32), off, 64);
        ext |= ((u64)hi << 32) | lo;
      }
      const u32 tlo = (u32)Tg, thi = (u32)(Tg >> 32);
      u64 rem = myvalid & ~ext;
      u64 cand = rem & nz;
      while (cand) {
        int i = __ffsll((long long)cand) - 1;
        cand &= cand - 1;  // clear bit i
        if ((rem >> i) & 1ull) {
          u32 rlo = __builtin_amdgcn_readlane(tlo, i);
          u32 rhi = __builtin_amdgcn_readlane(thi, i);
          u64 row = ((u64)rhi << 32) | rlo;  // bits only > i (diag-masked)
          rem &= ~row;
          cand &= ~row;
        }
      }
      if (lane == 0) keepb[g] = rem;
    }
    __syncthreads();
    if (wv > g) {
      u64 kg = keepb[g];  // broadcast LDS read
      if ((kg >> lane) & 1ull) ext_partial |= Tg;
    }
  }
}

// ---------------------------------------------------------------------------
// Parallel boundary-bin select over a 4096-bin LDS histogram (1024 threads).
// ---------------------------------------------------------------------------
__device__ __forceinline__ void suffix_select(const u32* __restrict__ hist,
                                              u32* __restrict__ aux,
                                              u32 base, u32 K,
                                              int* out_bin, u32* out_next) {
  const int t = threadIdx.x;  // 1024
  u32 h0 = hist[4 * t], h1 = hist[4 * t + 1];
  u32 h2 = hist[4 * t + 2], h3 = hist[4 * t + 3];
  aux[t] = h0 + h1 + h2 + h3;
  __syncthreads();
  for (int off = 1; off < 1024; off <<= 1) {
    u32 v = aux[t] + ((t + off < 1024) ? aux[t + off] : 0u);
    __syncthreads();
    aux[t] = v;
    __syncthreads();
  }
  if (t == 0 && base + aux[0] < K) { *out_bin = -1; *out_next = base; }
  u32 up = (t < 1023) ? aux[t + 1] : 0u;
  u32 s3 = h3 + up;
  u32 s2 = h2 + s3;
  u32 s1 = h1 + s2;
  u32 s0 = h0 + s1;
  u32 c0 = base + s0, c1 = base + s1, c2 = base + s2, c3 = base + s3;
  u32 c4 = base + up;
  if (c0 >= K && c1 < K) { *out_bin = 4 * t;     *out_next = c1; }
  if (c1 >= K && c2 < K) { *out_bin = 4 * t + 1; *out_next = c2; }
  if (c2 >= K && c3 < K) { *out_bin = 4 * t + 2; *out_next = c3; }
  if (c3 >= K && c4 < K) { *out_bin = 4 * t + 3; *out_next = c4; }
  __syncthreads();
}

// ===========================================================================
// COOPERATIVE MEGA-KERNEL: the whole pipeline, 1 launch, 6 grid syncs.
// 240 blocks x 1024 threads (1 block/CU co-resident; 52 KB LDS union).
// All phase bodies are the validated R4 kernels re-plumbed.
// ===========================================================================
template <bool S1, bool S2>
__global__ __launch_bounds__(1024) void k_mega(
    const float* __restrict__ cls, const float* __restrict__ boxes,
    float* __restrict__ out,
    float* __restrict__ score1, int* __restrict__ idx1, int* __restrict__ keep1,
    float* __restrict__ sel_score, int* __restrict__ sel_cls,
    int* __restrict__ sel_orig,
    u32* __restrict__ hdr, u64* __restrict__ cand,
    u64* __restrict__ mask1, u64* __restrict__ mask2,
    float4* __restrict__ cor1, float4* __restrict__ cor2,
    float m1a, float m0a, float m1b, float m0b) {
  cg::grid_group grid = cg::this_grid();
  const int tid = threadIdx.x;
  const int bid = blockIdx.x;
  const int wave = tid >> 6, lane = tid & 63;

  __shared__ union U {
    struct { u32 lcnt[B_ * C_]; u32 lpre[B_ * C_ + 1]; u64 ekey[LCAP]; u32 emeta[LCAP]; } cp;
    struct { u32 hist[NBIN]; u32 aux[1024]; u64 buf[CAP]; } s;
    struct { float4 box4[1024]; float area[1024]; } bl;
    struct { u64 keepb[16]; short ord[K1_]; int lbase[17]; } sc;
  } sh;
  __shared__ u32 sh_ltot, sh_lovf, sh_ovf, sh_base, sh_T, sh_cnt, sh_next;
  __shared__ int sh_b1, sh_ordc;

  // ---------- phase 1: compact (grid-stride over the 512 chunks) ----------
  for (u32 ck = (u32)bid; ck < CBLK; ck += NBLK_) {
    if (tid < B_ * C_) sh.cp.lcnt[tid] = 0;
    if (tid == 0) { sh_ltot = 0; sh_lovf = 0; }
    __syncthreads();

    const u32 lo = ck * ((TOTAL_F4 + CBLK - 1) / CBLK);
    u32 hi = lo + ((TOTAL_F4 + CBLK - 1) / CBLK);
    if (hi > TOTAL_F4) hi = TOTAL_F4;

    const float4* p4 = (const float4*)cls;
    for (u32 f = lo + tid; f < hi; f += 1024) {
      float4 v = p4[f];
      u32 e = f * 4u;
      float vs[4] = {v.x, v.y, v.z, v.w};
#pragma unroll
      for (int j = 0; j < 4; ++j) {
        float sv = vs[j];
        if (sv >= T0_F) {
          u32 g = e + (u32)j;
          u32 gi = g / (u32)C_;
          u32 c = g - gi * (u32)C_;
          u32 bi = gi / (u32)N_;
          u32 i = gi - bi * (u32)N_;
          u32 slice = bi * (u32)C_ + c;
          u32 rank = atomicAdd(&sh.cp.lcnt[slice], 1u);
          u32 pos = atomicAdd(&sh_ltot, 1u);
          if (pos < LCAP) {
            sh.cp.ekey[pos] = ((u64)__float_as_uint(sv) << 32) | (u32)(~i);
            sh.cp.emeta[pos] = (slice << 16) | rank;
          } else {
            sh_lovf = 1;
          }
        }
      }
    }
    __syncthreads();

    if (tid < B_ * C_) sh.cp.lpre[tid + 1] = sh.cp.lcnt[tid];
    if (tid == 0) sh.cp.lpre[0] = 0;
    __syncthreads();
    for (int off = 1; off < B_ * C_; off <<= 1) {
      u32 v = 0;
      const bool act = (tid >= off && tid <= B_ * C_);
      if (act) v = sh.cp.lpre[tid - off];
      __syncthreads();
      if (act) sh.cp.lpre[tid] += v;
      __syncthreads();
    }

    u32 tot = sh_ltot;
    if (tot > LCAP) tot = LCAP;
    u64* seg = cand + (size_t)ck * LCAP;
    for (u32 p = tid; p < tot; p += 1024) {
      u32 mta = sh.cp.emeta[p];
      u32 slice = mta >> 16;
      u32 rank = mta & 0xFFFFu;
      u32 dst = sh.cp.lpre[slice] + rank;
      if (dst < LCAP) seg[dst] = sh.cp.ekey[p];
    }
    if (tid <= B_ * C_) hdr[ck * HDRW + tid] = sh.cp.lpre[tid];
    if (tid == 0) hdr[ck * HDRW + 81] = sh_lovf;
    __syncthreads();
  }
  __threadfence();
  grid.sync();

  // ---------- phase 2: per-slice top-1000 select + corner prep ----------
  if (bid < B_ * C_) {
    const int slice = bid;
    u32* cnts = sh.s.hist;            // [512]
    u32* starts = sh.s.hist + 512;    // [512]
    u32* pre = sh.s.hist + 1024;      // [513]

    if (tid == 0) sh_ovf = 0;
    __syncthreads();
    if (tid < CBLK) {
      const u32* h = hdr + (size_t)tid * HDRW;
      u32 a = h[slice], b2 = h[slice + 1];
      starts[tid] = a;
      cnts[tid] = b2 - a;
      pre[tid + 1] = b2 - a;
      if (h[81]) sh_ovf = 1;
    }
    if (tid == 0) pre[0] = 0;
    __syncthreads();
    for (int off = 1; off < CBLK; off <<= 1) {
      u32 v = 0;
      const bool act = (tid >= off && tid <= CBLK);
      if (act) v = pre[tid - off];
      __syncthreads();
      if (act) pre[tid] += v;
      __syncthreads();
    }
    const u32 mm = pre[CBLK];
    const bool fastp = (sh_ovf == 0) && mm >= (u32)K1_ && mm <= (u32)CAP_C;

    float os = -1.0f; int ooi = 0;
    if (fastp) {
      if (tid < CBLK) {
        u32 n = cnts[tid];
        u32 base2 = pre[tid];
        const u64* src = cand + (size_t)tid * LCAP + starts[tid];
        for (u32 r = 0; r < n; ++r) sh.s.buf[base2 + r] = src[r];
      }
      __syncthreads();
      const u32 nn = next_pow2_ge(mm, 1024u, (u32)CAP_C);
      for (u32 i2 = tid; i2 < nn; i2 += 1024)
        if (i2 >= mm) sh.s.buf[i2] = 0ull;
      __syncthreads();
      bitonic_sort_desc(sh.s.buf, nn, tid, 1024);
      if (tid < K1_) {
        u64 e = sh.s.buf[tid];
        u32 k = (u32)(e >> 32);
        os = __uint_as_float(k);     // fast path: k != 0 always (s >= T0)
        ooi = (int)(~(u32)e);
      }
    } else {
      // exact fallback: two-level histogram select over the full column
      const int b = slice / C_, c = slice % C_;
      for (int i = tid; i < NBIN; i += 1024) sh.s.hist[i] = 0;
      __syncthreads();
      for (int i = tid; i < N_; i += 1024) {
        float sv = cls[((size_t)b * N_ + i) * C_ + c];
        if (sv >= MIN_CONF_F) atomicAdd(&sh.s.hist[__float_as_uint(sv) >> 19], 1u);
      }
      __syncthreads();
      if (tid == 0) {
        u32 cum = 0; int b1 = -1; u32 base = 0;
        for (int bin = NBIN - 1; bin >= 0; --bin) {
          cum += sh.s.hist[bin];
          if (cum >= (u32)K1_) { b1 = bin; base = cum - sh.s.hist[bin]; break; }
        }
        sh_b1 = b1; sh_base = base;
        if (b1 < 0) sh_T = 0;
      }
      __syncthreads();
      const int b1 = sh_b1;
      if (b1 >= 0) {
        const u32 base = sh_base;
        for (int i = tid; i < NBIN; i += 1024) sh.s.hist[i] = 0;
        __syncthreads();
        for (int i = tid; i < N_; i += 1024) {
          float sv = cls[((size_t)b * N_ + i) * C_ + c];
          if (sv >= MIN_CONF_F) {
            u32 k = __float_as_uint(sv);
            if ((int)(k >> 19) == b1) atomicAdd(&sh.s.hist[(k >> 7) & 0xFFFu], 1u);
          }
        }
        __syncthreads();
        if (tid == 0) {
          u32 cum = base;
          u32 T = ((u32)b1) << 19;
          for (int bin = NBIN - 1; bin >= 0; --bin) {
            cum += sh.s.hist[bin];
            if (cum >= (u32)K1_) { T = (((u32)b1) << 19) | (((u32)bin) << 7); break; }
          }
          sh_T = T;
        }
        __syncthreads();
      }
      if (tid == 0) sh_cnt = 0;
      __syncthreads();
      const u32 T = sh_T;
      for (int i = tid; i < N_; i += 1024) {
        float sv = cls[((size_t)b * N_ + i) * C_ + c];
        if (sv >= MIN_CONF_F) {
          u32 k = __float_as_uint(sv);
          if (k >= T) {
            u32 pos = atomicAdd(&sh_cnt, 1u);
            if (pos < CAP) sh.s.buf[pos] = ((u64)k << 32) | (u32)(~(u32)i);
          }
        }
      }
      __syncthreads();
      u32 m2 = sh_cnt; if (m2 > CAP) m2 = CAP;
      for (int i = tid; i < CAP; i += 1024)
        if ((u32)i >= m2) sh.s.buf[i] = 0ull;
      __syncthreads();
      bitonic_sort_desc(sh.s.buf, CAP, tid, 1024);
      if (tid < K1_) {
        u64 e = sh.s.buf[tid];
        u32 k = (u32)(e >> 32);
        if (k != 0) { os = __uint_as_float(k); ooi = (int)(~(u32)e); }
      }
    }
    if (tid < K1_) {
      score1[slice * K1_ + tid] = os;
      idx1[slice * K1_ + tid] = ooi;
    }
    prep_write(boxes + (size_t)(slice / C_) * N_ * 4, os, ooi, cor1,
               (slice << 10) + tid);
  }
  __threadfence();
  grid.sync();

  // ---------- phase 3: pass-1 mask build (3 blocks per slice) ----------
  {
    const int slice = bid % (B_ * C_);
    const int sub = bid / (B_ * C_);   // 0..2
    {
      const int p = tid;  // 1024 threads: one corner each
      const float4 c = cor1[(slice << 10) + p];
      sh.bl.box4[p] = c;
      sh.bl.area[p] = (c.z - c.x) * (c.w - c.y);
    }
    __syncthreads();
    u64* mg = mask1 + (size_t)slice * (NTILE * 64);
    for (int k = wave; ; k += 16) {
      const int tt = sub + 3 * k;
      if (tt >= NTILE) break;
      build_tile<S1>(sh.bl.box4, sh.bl.area, tt, lane, m1a, m0a, mg);
    }
  }
  __threadfence();
  grid.sync();

  // ---------- phase 4: pass-1 hierarchical scan ----------
  if (bid < B_ * C_) {
    const int slice = bid;
    float sv = (tid < K1_) ? score1[slice * K1_ + tid] : -1.0f;
    scan_core(mask1 + (size_t)slice * (NTILE * 64), sv, sh.sc.keepb);
    __syncthreads();
    if (tid < K1_)
      keep1[slice * K1_ + tid] =
          (int)((sh.sc.keepb[tid >> 6] >> (tid & 63)) & 1ull);
  }
  __threadfence();
  grid.sync();

  // ---------- phase 5: per-batch top-1000 + pass-2 corner prep ----------
  if (bid < B_) {
    const int b = bid;
    for (int i = tid; i < NBIN; i += 1024) sh.s.hist[i] = 0;
    __syncthreads();
    for (int f = tid; f < N2_; f += 1024) {
      if (keep1[b * N2_ + f])
        atomicAdd(&sh.s.hist[__float_as_uint(score1[b * N2_ + f]) >> 19], 1u);
    }
    __syncthreads();
    suffix_select(sh.s.hist, sh.s.aux, 0u, (u32)K1_, &sh_b1, &sh_next);
    const int b1 = sh_b1;
    const u32 base = sh_next;

    if (b1 >= 0) {
      for (int i = tid; i < NBIN; i += 1024) sh.s.hist[i] = 0;
      if (tid == 0) sh_b1 = -2;
      __syncthreads();
      for (int f = tid; f < N2_; f += 1024) {
        if (keep1[b * N2_ + f]) {
          u32 k = __float_as_uint(score1[b * N2_ + f]);
          if ((int)(k >> 19) == b1) atomicAdd(&sh.s.hist[(k >> 7) & 0xFFFu], 1u);
        }
      }
      __syncthreads();
      suffix_select(sh.s.hist, sh.s.aux, base, (u32)K1_, &sh_b1, &sh_next);
      if (tid == 0) {
        int b2 = sh_b1;
        sh_T = (b2 >= 0) ? ((((u32)b1) << 19) | (((u32)b2) << 7))
                         : (((u32)b1) << 19);
      }
    } else {
      if (tid == 0) sh_T = 0;
    }
    if (tid == 0) sh_cnt = 0;
    __syncthreads();

    const u32 T = sh_T;
    for (int f = tid; f < N2_; f += 1024) {
      if (keep1[b * N2_ + f]) {
        u32 k = __float_as_uint(score1[b * N2_ + f]);
        if (k >= T) {
          u32 pos = atomicAdd(&sh_cnt, 1u);
          if (pos < CAP) sh.s.buf[pos] = ((u64)k << 32) | (u32)(~(u32)f);
        }
      }
    }
    __syncthreads();
    u32 m2 = sh_cnt; if (m2 > CAP) m2 = CAP;
    const u32 n = next_pow2_ge(m2, 1024u, (u32)CAP);
    for (u32 i = tid; i < n; i += 1024)
      if (i >= m2) sh.s.buf[i] = 0ull;
    __syncthreads();

    bitonic_sort_desc(sh.s.buf, n, tid, 1024);

    float os = -1.0f; int ooi = 0;
    if (tid < K1_) {
      u64 e = sh.s.buf[tid];
      u32 k = (u32)(e >> 32);
      float sv; int cls2, orig;
      if (k == 0) { sv = -1.0f; cls2 = 0; orig = 0; }
      else {
        sv = __uint_as_float(k);
        u32 f = ~(u32)e;
        cls2 = (int)(f / K1_);
        int slot = (int)(f - (u32)cls2 * K1_);
        orig = idx1[(b * C_ + cls2) * K1_ + slot];
      }
      sel_score[b * K1_ + tid] = sv;
      sel_cls[b * K1_ + tid] = cls2;
      sel_orig[b * K1_ + tid] = orig;
      os = sv; ooi = orig;
    }
    prep_write(boxes + (size_t)b * N_ * 4, os, ooi, cor2, (b << 10) + tid);
  }
  __threadfence();
  grid.sync();

  // ---------- phase 6: pass-2 mask build (30 blocks per batch) ----------
  {
    const int b = bid % B_;
    const int sub = bid / B_;          // 0..29
    {
      const int p = tid;
      const float4 c = cor2[(b << 10) + p];
      sh.bl.box4[p] = c;
      sh.bl.area[p] = (c.z - c.x) * (c.w - c.y);
    }
    __syncthreads();
    u64* mg = mask2 + (size_t)b * (NTILE * 64);
    for (int k = wave; ; k += 16) {
      const int tt = sub + 30 * k;
      if (tt >= NTILE) break;
      build_tile<S2>(sh.bl.box4, sh.bl.area, tt, lane, m1b, m0b, mg);
    }
  }
  __threadfence();
  grid.sync();

  // ---------- phase 7: pass-2 scan + ordered output ----------
  if (bid < B_) {
    const int b = bid;
    float sv = (tid < K1_) ? sel_score[b * K1_ + tid] : -1.0f;
    scan_core(mask2 + (size_t)b * (NTILE * 64), sv, sh.sc.keepb);
    __syncthreads();

    if (tid == 0) {
      int acc = 0;
      for (int wdx = 0; wdx < 16; ++wdx) {
        sh.sc.lbase[wdx] = acc;
        acc += __popcll(sh.sc.keepb[wdx]);
      }
      sh.sc.lbase[16] = acc;
      sh_ordc = acc;
    }
    __syncthreads();
    if (tid < 16) {
      u64 m = sh.sc.keepb[tid];
      int base = sh.sc.lbase[tid];
      while (m) {
        int bit = __ffsll((long long)m) - 1;
        sh.sc.ord[base++] = (short)((tid << 6) | bit);
        m &= m - 1;
      }
    }
    __syncthreads();

    for (int t = tid; t < K1_ * 6; t += 1024) out[(size_t)b * K1_ * 6 + t] = 0.0f;
    __syncthreads();

    const int cnt = sh_ordc;
    for (int q = tid; q < cnt; q += 1024) {
      int p = sh.sc.ord[q];
      int oi = sel_orig[b * K1_ + p];
      const float4 bp = *(const float4*)(boxes + ((size_t)b * N_ + oi) * 4);
      float* o = out + ((size_t)b * K1_ + q) * 6;
      o[0] = bp.x; o[1] = bp.y; o[2] = bp.z; o[3] = bp.w;
      o[4] = (float)sel_cls[b * K1_ + p];
      o[5] = sel_score[b * K1_ + p];
    }
  }
}

// ===========================================================================
// CLASSIC PATH (validated R4, verbatim behavior) — used if cooperative
// launch is unavailable.
// ===========================================================================
__global__ __launch_bounds__(256) void k_compact(const float* __restrict__ cls,
                                                 u64* __restrict__ cand,
                                                 u32* __restrict__ hdr) {
  __shared__ u32 lcnt[B_ * C_];
  __shared__ u32 lpre[B_ * C_ + 1];
  __shared__ u32 ltot;
  __shared__ u32 lovf;
  __shared__ u64 ekey[LCAP];
  __shared__ u32 emeta[LCAP];

  const int tid = threadIdx.x;
  const u32 bk = blockIdx.x;
  if (tid < B_ * C_) lcnt[tid] = 0;
  if (tid == 0) { ltot = 0; lovf = 0; }
  __syncthreads();

  const u32 lo = bk * ((TOTAL_F4 + CBLK - 1) / CBLK);
  u32 hi = lo + ((TOTAL_F4 + CBLK - 1) / CBLK);
  if (hi > TOTAL_F4) hi = TOTAL_F4;

  const float4* p4 = (const float4*)cls;
  for (u32 f = lo + tid; f < hi; f += 256) {
    float4 v = p4[f];
    u32 e = f * 4u;
    float vs[4] = {v.x, v.y, v.z, v.w};
#pragma unroll
    for (int j = 0; j < 4; ++j) {
      float s = vs[j];
      if (s >= T0_F) {
        u32 g = e + (u32)j;
        u32 gi = g / (u32)C_;
        u32 c = g - gi * (u32)C_;
        u32 bi = gi / (u32)N_;
        u32 i = gi - bi * (u32)N_;
        u32 slice = bi * (u32)C_ + c;
        u32 rank = atomicAdd(&lcnt[slice], 1u);
        u32 pos = atomicAdd(&ltot, 1u);
        if (pos < LCAP) {
          ekey[pos] = ((u64)__float_as_uint(s) << 32) | (u32)(~i);
          emeta[pos] = (slice << 16) | rank;
        } else {
          lovf = 1;
        }
      }
    }
  }
  __syncthreads();

  if (tid < B_ * C_) lpre[tid + 1] = lcnt[tid];
  if (tid == 0) lpre[0] = 0;
  __syncthreads();
  for (int off = 1; off < B_ * C_; off <<= 1) {
    u32 v = 0;
    const bool act = (tid >= off && tid <= B_ * C_);
    if (act) v = lpre[tid - off];
    __syncthreads();
    if (act) lpre[tid] += v;
    __syncthreads();
  }

  u32 tot = ltot;
  if (tot > LCAP) tot = LCAP;
  u64* seg = cand + (size_t)bk * LCAP;
  for (u32 p = tid; p < tot; p += 256) {
    u32 mta = emeta[p];
    u32 slice = mta >> 16;
    u32 rank = mta & 0xFFFFu;
    u32 dst = lpre[slice] + rank;
    if (dst < LCAP) seg[dst] = ekey[p];
  }
  if (tid <= B_ * C_) hdr[bk * HDRW + tid] = lpre[tid];
  if (tid == 0) hdr[bk * HDRW + 81] = lovf;
}

__global__ __launch_bounds__(1024) void k_sel(const float* __restrict__ cls,
                                              const u64* __restrict__ cand,
                                              const u32* __restrict__ hdr,
                                              float* __restrict__ score1,
                                              int* __restrict__ idx1,
                                              const float* __restrict__ boxes,
                                              float4* __restrict__ cor1,
                                              int do_prep) {
  const int slice = blockIdx.x;
  const int tid = threadIdx.x;
  const int bd = 1024;

  __shared__ u32 hist[NBIN];
  __shared__ u64 buf[CAP];
  __shared__ int sh_b1;
  __shared__ u32 sh_base, sh_T, sh_cnt, sh_ovf;

  u32* cnts = hist;
  u32* starts = hist + 512;
  u32* pre = hist + 1024;

  if (tid == 0) sh_ovf = 0;
  __syncthreads();
  if (tid < CBLK) {
    const u32* h = hdr + (size_t)tid * HDRW;
    u32 a = h[slice], b2 = h[slice + 1];
    starts[tid] = a;
    cnts[tid] = b2 - a;
    pre[tid + 1] = b2 - a;
    if (h[81]) sh_ovf = 1;
  }
  if (tid == 0) pre[0] = 0;
  __syncthreads();
  for (int off = 1; off < CBLK; off <<= 1) {
    u32 v = 0;
    const bool act = (tid >= off && tid <= CBLK);
    if (act) v = pre[tid - off];
    __syncthreads();
    if (act) pre[tid] += v;
    __syncthreads();
  }
  const u32 m = pre[CBLK];
  const bool fast = (sh_ovf == 0) && m >= (u32)K1_ && m <= (u32)CAP_C;

  if (fast) {
    if (tid < CBLK) {
      u32 n = cnts[tid];
      u32 base = pre[tid];
      const u64* src = cand + (size_t)tid * LCAP + starts[tid];
      for (u32 r = 0; r < n; ++r) buf[base + r] = src[r];
    }
    __syncthreads();
    const u32 nn = next_pow2_ge(m, 1024u, (u32)CAP_C);
    for (u32 i2 = tid; i2 < nn; i2 += bd)
      if (i2 >= m) buf[i2] = 0ull;
    __syncthreads();

    bitonic_sort_desc(buf, nn, tid, bd);

    float os = -1.0f; int ooi = 0;
    if (tid < K1_) {
      u64 e = buf[tid];
      u32 k = (u32)(e >> 32);
      os = __uint_as_float(k);
      ooi = (int)(~(u32)e);
      score1[slice * K1_ + tid] = os;
      idx1[slice * K1_ + tid] = ooi;
    }
    if (do_prep)
      prep_write(boxes + (size_t)(slice / C_) * N_ * 4, os, ooi, cor1,
                 (slice << 10) + tid);
    return;
  }

  const int b = slice / C_, c = slice % C_;

  for (int i = tid; i < NBIN; i += bd) hist[i] = 0;
  __syncthreads();
  for (int i = tid; i < N_; i += bd) {
    float s = cls[((size_t)b * N_ + i) * C_ + c];
    if (s >= MIN_CONF_F) atomicAdd(&hist[__float_as_uint(s) >> 19], 1u);
  }
  __syncthreads();
  if (tid == 0) {
    u32 cum = 0; int b1 = -1; u32 base = 0;
    for (int bin = NBIN - 1; bin >= 0; --bin) {
      cum += hist[bin];
      if (cum >= (u32)K1_) { b1 = bin; base = cum - hist[bin]; break; }
    }
    sh_b1 = b1; sh_base = base;
    if (b1 < 0) sh_T = 0;
  }
  __syncthreads();
  const int b1 = sh_b1;

  if (b1 >= 0) {
    const u32 base = sh_base;
    for (int i = tid; i < NBIN; i += bd) hist[i] = 0;
    __syncthreads();
    for (int i = tid; i < N_; i += bd) {
      float s = cls[((size_t)b * N_ + i) * C_ + c];
      if (s >= MIN_CONF_F) {
        u32 k = __float_as_uint(s);
        if ((int)(k >> 19) == b1) atomicAdd(&hist[(k >> 7) & 0xFFFu], 1u);
      }
    }
    __syncthreads();
    if (tid == 0) {
      u32 cum = base;
      u32 T = ((u32)b1) << 19;
      for (int bin = NBIN - 1; bin >= 0; --bin) {
        cum += hist[bin];
        if (cum >= (u32)K1_) { T = (((u32)b1) << 19) | (((u32)bin) << 7); break; }
      }
      sh_T = T;
    }
    __syncthreads();
  }

  if (tid == 0) sh_cnt = 0;
  __syncthreads();
  const u32 T = sh_T;
  for (int i = tid; i < N_; i += bd) {
    float s = cls[((size_t)b * N_ + i) * C_ + c];
    if (s >= MIN_CONF_F) {
      u32 k = __float_as_uint(s);
      if (k >= T) {
        u32 pos = atomicAdd(&sh_cnt, 1u);
        if (pos < CAP) buf[pos] = ((u64)k << 32) | (u32)(~(u32)i);
      }
    }
  }
  __syncthreads();
  u32 mm = sh_cnt; if (mm > CAP) mm = CAP;
  for (int i = tid; i < CAP; i += bd)
    if ((u32)i >= mm) buf[i] = 0ull;
  __syncthreads();

  for (u32 kk = 2; kk <= CAP; kk <<= 1) {
    for (u32 j = kk >> 1; j > 0; j >>= 1) {
      for (u32 i = tid; i < CAP; i += bd) {
        u32 l = i ^ j;
        if (l > i) {
          u64 a = buf[i], bb2 = buf[l];
          bool desc = ((i & kk) == 0);
          if (desc ? (a < bb2) : (a > bb2)) { buf[i] = bb2; buf[l] = a; }
        }
      }
      __syncthreads();
    }
  }

  float os = -1.0f; int ooi = 0;
  if (tid < K1_) {
    u64 e = buf[tid];
    u32 k = (u32)(e >> 32);
    if (k != 0) { os = __uint_as_float(k); ooi = (int)(~(u32)e); }
    score1[slice * K1_ + tid] = os;
    idx1[slice * K1_ + tid] = ooi;
  }
  if (do_prep)
    prep_write(boxes + (size_t)(slice / C_) * N_ * 4, os, ooi, cor1,
               (slice << 10) + tid);
}

template <bool STRICT>
__global__ __launch_bounds__(256) void k_nms_build(const float4* __restrict__ cor,
                                                   float m1, float m0,
                                                   u64* __restrict__ maskg) {
  __shared__ float4 box4[1024];
  __shared__ float area[1024];
  const int blk = blockIdx.x;
  const int slice = blk / NB_;
  const int sub = blk - slice * NB_;
  const int tid = threadIdx.x, wave = tid >> 6, lane = tid & 63;

  for (int p = tid; p < 1024; p += 256) {
    const float4 c = cor[(slice << 10) + p];
    box4[p] = c;
    area[p] = (c.z - c.x) * (c.w - c.y);
  }
  __syncthreads();

  u64* mg = maskg + (size_t)slice * (NTILE * 64);

  for (int k = wave; k < TPB_; k += 4) {
    const int tt = sub * TPB_ + k;
    if (tt >= NTILE) break;
    build_tile<STRICT>(box4, area, tt, lane, m1, m0, mg);
  }
}

__global__ __launch_bounds__(1024) void k_nms_scan1(const u64* __restrict__ maskg,
                                                    const float* __restrict__ score1,
                                                    int* __restrict__ keep1) {
  __shared__ u64 keepb[16];
  const int slice = blockIdx.x;
  const int tid = threadIdx.x;
  float s = (tid < K1_) ? score1[slice * K1_ + tid] : -1.0f;
  scan_core(maskg + (size_t)slice * (NTILE * 64), s, keepb);
  __syncthreads();
  if (tid < K1_)
    keep1[slice * K1_ + tid] = (int)((keepb[tid >> 6] >> (tid & 63)) & 1ull);
}

__global__ __launch_bounds__(1024) void k_nms_scan2(const u64* __restrict__ maskg,
                                                    const float* __restrict__ sel_score,
                                                    const int* __restrict__ sel_cls,
                                                    const int* __restrict__ sel_orig,
                                                    const float* __restrict__ boxes,
                                                    float* __restrict__ out) {
  __shared__ u64 keepb[16];
  __shared__ short ord[K1_];
  __shared__ int lbase[17];
  __shared__ int ordc;
  const int b = blockIdx.x;
  const int tid = threadIdx.x;
  float s = (tid < K1_) ? sel_score[b * K1_ + tid] : -1.0f;
  scan_core(maskg + (size_t)b * (NTILE * 64), s, keepb);
  __syncthreads();

  if (tid == 0) {
    int acc = 0;
    for (int wdx = 0; wdx < 16; ++wdx) {
      lbase[wdx] = acc;
      acc += __popcll(keepb[wdx]);
    }
    lbase[16] = acc;
    ordc = acc;
  }
  __syncthreads();
  if (tid < 16) {
    u64 m = keepb[tid];
    int base = lbase[tid];
    while (m) {
      int bit = __ffsll((long long)m) - 1;
      ord[base++] = (short)((tid << 6) | bit);
      m &= m - 1;
    }
  }
  __syncthreads();

  for (int t = tid; t < K1_ * 6; t += 1024) out[(size_t)b * K1_ * 6 + t] = 0.0f;
  __syncthreads();

  const int cnt = ordc;
  for (int q = tid; q < cnt; q += 1024) {
    int p = ord[q];
    int oi = sel_orig[b * K1_ + p];
    const float4 bp = *(const float4*)(boxes + ((size_t)b * N_ + oi) * 4);
    float* o = out + ((size_t)b * K1_ + q) * 6;
    o[0] = bp.x; o[1] = bp.y; o[2] = bp.z; o[3] = bp.w;
    o[4] = (float)sel_cls[b * K1_ + p];
    o[5] = sel_score[b * K1_ + p];
  }
}

__global__ __launch_bounds__(1024) void k_topk2(const float* __restrict__ score1,
                                                const int* __restrict__ idx1,
                                                const int* __restrict__ keep1,
                                                float* __restrict__ sel_score,
                                                int* __restrict__ sel_cls,
                                                int* __restrict__ sel_orig,
                                                const float* __restrict__ boxes,
                                                float4* __restrict__ cor2,
                                                int do_prep) {
  const int b = blockIdx.x;
  const int tid = threadIdx.x;

  __shared__ u32 hist[NBIN];
  __shared__ u32 aux[1024];
  __shared__ u64 buf[CAP];
  __shared__ int sh_bin;
  __shared__ u32 sh_next;
  __shared__ u32 sh_T, sh_cnt;

  for (int i = tid; i < NBIN; i += 1024) hist[i] = 0;
  __syncthreads();
  for (int f = tid; f < N2_; f += 1024) {
    if (keep1[b * N2_ + f])
      atomicAdd(&hist[__float_as_uint(score1[b * N2_ + f]) >> 19], 1u);
  }
  __syncthreads();
  suffix_select(hist, aux, 0u, (u32)K1_, &sh_bin, &sh_next);
  const int b1 = sh_bin;
  const u32 base = sh_next;

  if (b1 >= 0) {
    for (int i = tid; i < NBIN; i += 1024) hist[i] = 0;
    if (tid == 0) sh_bin = -2;
    __syncthreads();
    for (int f = tid; f < N2_; f += 1024) {
      if (keep1[b * N2_ + f]) {
        u32 k = __float_as_uint(score1[b * N2_ + f]);
        if ((int)(k >> 19) == b1) atomicAdd(&hist[(k >> 7) & 0xFFFu], 1u);
      }
    }
    __syncthreads();
    suffix_select(hist, aux, base, (u32)K1_, &sh_bin, &sh_next);
    if (tid == 0) {
      int b2 = sh_bin;
      sh_T = (b2 >= 0) ? ((((u32)b1) << 19) | (((u32)b2) << 7))
                       : (((u32)b1) << 19);
    }
  } else {
    if (tid == 0) sh_T = 0;
  }
  if (tid == 0) sh_cnt = 0;
  __syncthreads();

  const u32 T = sh_T;
  for (int f = tid; f < N2_; f += 1024) {
    if (keep1[b * N2_ + f]) {
      u32 k = __float_as_uint(score1[b * N2_ + f]);
      if (k >= T) {
        u32 pos = atomicAdd(&sh_cnt, 1u);
        if (pos < CAP) buf[pos] = ((u64)k << 32) | (u32)(~(u32)f);
      }
    }
  }
  __syncthreads();
  u32 m = sh_cnt; if (m > CAP) m = CAP;
  const u32 n = next_pow2_ge(m, 1024u, (u32)CAP);
  for (u32 i = tid; i < n; i += 1024)
    if (i >= m) buf[i] = 0ull;
  __syncthreads();

  bitonic_sort_desc(buf, n, tid, 1024);

  float os = -1.0f; int ooi = 0;
  if (tid < K1_) {
    u64 e = buf[tid];
    u32 k = (u32)(e >> 32);
    float s; int cls, orig;
    if (k == 0) { s = -1.0f; cls = 0; orig = 0; }
    else {
      s = __uint_as_float(k);
      u32 f = ~(u32)e;
      cls = (int)(f / K1_);
      int slot = (int)(f - (u32)cls * K1_);
      orig = idx1[(b * C_ + cls) * K1_ + slot];
    }
    sel_score[b * K1_ + tid] = s;
    sel_cls[b * K1_ + tid] = cls;
    sel_orig[b * K1_ + tid] = orig;
    os = s; ooi = orig;
  }
  if (do_prep)
    prep_write(boxes + (size_t)b * N_ * 4, os, ooi, cor2, (b << 10) + tid);
}

// ===========================================================================
// Fused NMS (fallback when ws is too small) — validated R8 code, verbatim.
// ===========================================================================
__device__ __forceinline__ void nms_run(const float* __restrict__ scores,
                                        const int* __restrict__ origs,
                                        const float* __restrict__ boxesB,
                                        float thr,
                                        float4* box4, float* area,
                                        u64* mask, u64* validw, u64* keepw) {
  const int tid = threadIdx.x;
  const int wave = tid >> 6, lane = tid & 63;

  {
    const int p = tid;
    float s = (p < K1_) ? scores[p] : -1.0f;
    bool v = (s >= MIN_CONF_F);
    float cx = 0.f, cy = 0.f, w = 0.f, h = 0.f;
    if (v) {
      const float4 bp = *(const float4*)(boxesB + (size_t)origs[p] * 4);
      cx = bp.x; cy = bp.y; w = bp.z; h = bp.w;
    }
    float y1 = cy - h * 0.5f, x1 = cx - w * 0.5f;
    float y2 = cy + h * 0.5f, x2 = cx + w * 0.5f;
    box4[p] = make_float4(y1, x1, y2, x2);
    area[p] = (y2 - y1) * (x2 - x1);
    u64 mb = __ballot(v);
    if (lane == 0) validw[wave] = mb;
  }
  __syncthreads();

  const float cf = thr;
  const float cnext = __uint_as_float(__float_as_uint(cf) + 1u);
  const double M = ((double)cf + (double)cnext) * 0.5;
  const bool strict = ((__float_as_uint(cf) & 1u) == 0u);

  const int ss = wave & 3, qq = wave >> 2;
  int col;
  if (qq == 0) col = ss;
  else if (qq == 1) col = 7 - ss;
  else if (qq == 2) col = 8 + ss;
  else col = 15 - ss;

  u64 vw = validw[tid & 15];
  u64 supp = 0;

  for (int seg = 0; seg < 4; ++seg) {
    const int ibase = seg * SEGROWS;
    const int lim = (K1_ - ibase < SEGROWS) ? (K1_ - ibase) : SEGROWS;
    const int rtg0 = ibase >> 6;
    int ntile = col - rtg0 + 1;
    if (ntile < 0) ntile = 0;
    if (ntile > 4) ntile = 4;

    if (ntile > 0) {
      float4 ib[4];
      float ia[4];
#pragma unroll
      for (int r = 0; r < 4; ++r) {
        if (r < ntile) {
          const int i = ibase + (r << 6) + lane;
          ib[r] = box4[i];
          ia[r] = area[i];
        }
      }
      u32 mhi[4] = {0, 0, 0, 0}, mlo[4] = {0, 0, 0, 0};
      const float4* jcol = &box4[col << 6];

      for (int j = 63; j >= 32; --j) {
        const float4 jb = jcol[j];
        const float ja = (jb.z - jb.x) * (jb.w - jb.y);
#pragma unroll
        for (int r = 0; r < 4; ++r) {
          if (r < ntile) {
            float ih = fminf(ib[r].z, jb.z) - fmaxf(ib[r].x, jb.x);
            ih = fmaxf(ih, 0.0f);
            float iw_ = fminf(ib[r].w, jb.w) - fmaxf(ib[r].y, jb.y);
            iw_ = fmaxf(iw_, 0.0f);
            float inter = ih * iw_;
            float den = fmaxf((ia[r] + ja) - inter, 1e-8f);
            bool p_ = strict ? ((double)inter > M * (double)den)
                             : ((double)inter >= M * (double)den);
            mhi[r] = (mhi[r] << 1) | (p_ ? 1u : 0u);
          }
        }
      }
      for (int j = 31; j >= 0; --j) {
        const float4 jb = jcol[j];
        const float ja = (jb.z - jb.x) * (jb.w - jb.y);
#pragma unroll
        for (int r = 0; r < 4; ++r) {
          if (r < ntile) {
            float ih = fminf(ib[r].z, jb.z) - fmaxf(ib[r].x, jb.x);
            ih = fmaxf(ih, 0.0f);
            float iw_ = fminf(ib[r].w, jb.w) - fmaxf(ib[r].y, jb.y);
            iw_ = fmaxf(iw_, 0.0f);
            float inter = ih * iw_;
            float den = fmaxf((ia[r] + ja) - inter, 1e-8f);
            bool p_ = strict ? ((double)inter > M * (double)den)
                             : ((double)inter >= M * (double)den);
            mlo[r] = (mlo[r] << 1) | (p_ ? 1u : 0u);
          }
        }
      }
#pragma unroll
      for (int r = 0; r < 4; ++r) {
        if (r < ntile) {
          u64 m = ((u64)mhi[r] << 32) | (u64)mlo[r];
          if (rtg0 + r == col)
            m &= (lane == 63) ? 0ull : (~0ull << (lane + 1));
          const int il = (r << 6) | lane;
          mask[il * 16 + (col ^ (il & 15))] = m;
        }
      }
    }
    __syncthreads();

    if (tid < 64) {
      const int l = tid & 15;
      u64 r0 = 0, r1 = 0, r2 = 0, r3 = 0;
      if (l >= ((ibase + 0) >> 6)) r0 = mask[0 * 16 + (l ^ 0)];
      if (l >= ((ibase + 1) >> 6)) r1 = mask[1 * 16 + (l ^ 1)];
      if (l >= ((ibase + 2) >> 6)) r2 = mask[2 * 16 + (l ^ 2)];
      if (l >= ((ibase + 3) >> 6)) r3 = mask[3 * 16 + (l ^ 3)];
      for (int il = 0; il < lim; il += 4) {
        const int i0 = ibase + il;
        const int n0 = (il + 4 < lim) ? il + 4 : il;
        const int n1 = (il + 5 < lim) ? il + 5 : il;
        const int n2 = (il + 6 < lim) ? il + 6 : il;
        const int n3 = (il + 7 < lim) ? il + 7 : il;
        u64 m0 = r0, m1 = r1, m2 = r2, m3 = r3;
        r0 = (l >= ((ibase + n0) >> 6)) ? mask[n0 * 16 + (l ^ (n0 & 15))] : 0ull;
        r1 = (l >= ((ibase + n1) >> 6)) ? mask[n1 * 16 + (l ^ (n1 & 15))] : 0ull;
        r2 = (l >= ((ibase + n2) >> 6)) ? mask[n2 * 16 + (l ^ (n2 & 15))] : 0ull;
        r3 = (l >= ((ibase + n3) >> 6)) ? mask[n3 * 16 + (l ^ (n3 & 15))] : 0ull;
        bool a;
        a = (tid == (i0 >> 6)) && (((vw & ~supp) >> (i0 & 63)) & 1ull);
        if (__any(a)) supp |= m0;
        a = (tid == ((i0 + 1) >> 6)) && (((vw & ~supp) >> ((i0 + 1) & 63)) & 1ull);
        if (__any(a)) supp |= m1;
        a = (tid == ((i0 + 2) >> 6)) && (((vw & ~supp) >> ((i0 + 2) & 63)) & 1ull);
        if (__any(a)) supp |= m2;
        a = (tid == ((i0 + 3) >> 6)) && (((vw & ~supp) >> ((i0 + 3) & 63)) & 1ull);
        if (__any(a)) supp |= m3;
      }
    }
    __syncthreads();
  }

  if (tid < 16) keepw[tid] = vw & ~supp;
}

__global__ __launch_bounds__(1024) void k_nms1(const float* __restrict__ boxes,
                                               const float* __restrict__ score1,
                                               const int* __restrict__ idx1,
                                               int* __restrict__ keep1) {
  __shared__ float4 box4[1024];
  __shared__ float area[1024];
  __shared__ u64 mask[SEGROWS * 16];
  __shared__ u64 validw[16], keepw[16];

  const int slice = blockIdx.x;
  const int b = slice / C_;
  nms_run(score1 + slice * K1_, idx1 + slice * K1_,
          boxes + (size_t)b * N_ * 4, NMS_IOU_F,
          box4, area, mask, validw, keepw);
  __syncthreads();

  const int p = threadIdx.x;
  if (p < K1_)
    keep1[slice * K1_ + p] = (int)((keepw[p >> 6] >> (p & 63)) & 1ull);
}

__global__ __launch_bounds__(1024) void k_nms2_out(const float* __restrict__ boxes,
                                                   const float* __restrict__ sel_score,
                                                   const int* __restrict__ sel_cls,
                                                   const int* __restrict__ sel_orig,
                                                   float* __restrict__ out) {
  __shared__ float4 box4[1024];
  __shared__ float area[1024];
  __shared__ u64 mask[SEGROWS * 16];
  __shared__ u64 validw[16], keepw[16];
  __shared__ short ord[K1_];
  __shared__ int lbase[17];
  __shared__ int ordc;

  const int b = blockIdx.x;
  const int tid = threadIdx.x;
  nms_run(sel_score + b * K1_, sel_orig + b * K1_,
          boxes + (size_t)b * N_ * 4, POST_IOU_F,
          box4, area, mask, validw, keepw);
  __syncthreads();

  if (tid == 0) {
    int acc = 0;
    for (int wdx = 0; wdx < 16; ++wdx) {
      lbase[wdx] = acc;
      acc += __popcll(keepw[wdx]);
    }
    lbase[16] = acc;
    ordc = acc;
  }
  __syncthreads();
  if (tid < 16) {
    u64 m = keepw[tid];
    int base = lbase[tid];
    while (m) {
      int bit = __ffsll((long long)m) - 1;
      ord[base++] = (short)((tid << 6) | bit);
      m &= m - 1;
    }
  }
  __syncthreads();

  for (int t = tid; t < K1_ * 6; t += 1024) out[(size_t)b * K1_ * 6 + t] = 0.0f;
  __syncthreads();

  const int cnt = ordc;
  for (int q = tid; q < cnt; q += 1024) {
    int p = ord[q];
    int oi = sel_orig[b * K1_ + p];
    const float4 bp = *(const float4*)(boxes + ((size_t)b * N_ + oi) * 4);
    float* o = out + ((size_t)b * K1_ + q) * 6;
    o[0] = bp.x; o[1] = bp.y; o[2] = bp.z; o[3] = bp.w;
    o[4] = (float)sel_cls[b * K1_ + p];
    o[5] = sel_score[b * K1_ + p];
  }
}

// ---------------------------------------------------------------------------
static inline void m_split(float cf, float* m1, float* m0, bool* strict) {
  u32 b; memcpy(&b, &cf, 4);
  u32 nb = b + 1; float cn; memcpy(&cn, &nb, 4);
  double M = ((double)cf + (double)cn) * 0.5;
  *m1 = (float)M;
  *m0 = (float)(M - (double)*m1);
  *strict = ((b & 1u) == 0u);
}

extern "C" void kernel_launch(void* const* d_in, const int* in_sizes, int n_in,
                              void* d_out, int out_size, void* d_ws, size_t ws_size,
                              hipStream_t stream) {
  const float* cls = (const float*)d_in[0];    // (8,100000,10) f32
  const float* boxes = (const float*)d_in[1];  // (8,100000,4)  f32
  float* out = (float*)d_out;                  // (8,1000,6)    f32

  char* ws = (char*)d_ws;
  float* score1    = (float*)(ws);                     // 80000 f32
  int*   idx1      = (int*)(ws + 320000);              // 80000 i32
  int*   keep1     = (int*)(ws + 640000);              // 80000 i32
  float* sel_score = (float*)(ws + 960000);            // 8000 f32
  int*   sel_cls   = (int*)(ws + 992000);              // 8000 i32
  int*   sel_orig  = (int*)(ws + 1024000);             // 8000 i32
  u32*   hdr       = (u32*)(ws + 1056000);             // 512*84 u32   -> 1228032
  u64*   cand      = (u64*)(ws + 1228032);             // 512*512 u64  -> 3325184
  u64*   mask1     = (u64*)(ws + 3325184);             // 80*8704 u64  -> 8895744
  u64*   mask2     = (u64*)(ws + 3325184);             // aliases mask1 (dead before reuse)
  float4* cor1     = (float4*)(ws + 8895744);          // 80*1024 f4   -> 10206464
  float4* cor2     = (float4*)(ws + 8895744);          // aliases cor1 (dead before reuse)
  const size_t WS_NEED = 10206464;

  float m1a, m0a, m1b, m0b; bool sa, sb;
  m_split(NMS_IOU_F, &m1a, &m0a, &sa);   // 0.4f  -> strict = false
  m_split(POST_IOU_F, &m1b, &m0b, &sb);  // 0.65f -> strict = true

  static int coop_ok = -1;
  if (coop_ok < 0) {
    int v = 0, dev = 0;
    (void)hipGetDevice(&dev);
    if (hipDeviceGetAttribute(&v, hipDeviceAttributeCooperativeLaunch, dev) !=
        hipSuccess)
      v = 0;
    coop_ok = v;
  }

  if (coop_ok && ws_size >= WS_NEED) {
    void* args[] = {
        (void*)&cls, (void*)&boxes, (void*)&out,
        (void*)&score1, (void*)&idx1, (void*)&keep1,
        (void*)&sel_score, (void*)&sel_cls, (void*)&sel_orig,
        (void*)&hdr, (void*)&cand, (void*)&mask1, (void*)&mask2,
        (void*)&cor1, (void*)&cor2,
        (void*)&m1a, (void*)&m0a, (void*)&m1b, (void*)&m0b};
    const void* fn =
        sa ? (sb ? (const void*)k_mega<true, true>
                 : (const void*)k_mega<true, false>)
           : (sb ? (const void*)k_mega<false, true>
                 : (const void*)k_mega<false, false>);
    hipError_t e = hipLaunchCooperativeKernel(fn, dim3(NBLK_), dim3(1024),
                                              args, 0, stream);
    if (e == hipSuccess) return;
    // fall through to classic path on failure
  }

  const int do_fast = (ws_size >= WS_NEED) ? 1 : 0;

  hipLaunchKernelGGL(k_compact, dim3(CBLK), dim3(256), 0, stream,
                     cls, cand, hdr);
  hipLaunchKernelGGL(k_sel, dim3(B_ * C_), dim3(1024), 0, stream,
                     cls, cand, hdr, score1, idx1, boxes, cor1, do_fast);

  if (do_fast) {
    if (sa)
      hipLaunchKernelGGL(k_nms_build<true>, dim3(B_ * C_ * NB_), dim3(256), 0,
                         stream, cor1, m1a, m0a, mask1);
    else
      hipLaunchKernelGGL(k_nms_build<false>, dim3(B_ * C_ * NB_), dim3(256), 0,
                         stream, cor1, m1a, m0a, mask1);
    hipLaunchKernelGGL(k_nms_scan1, dim3(B_ * C_), dim3(1024), 0, stream,
                       mask1, score1, keep1);
    hipLaunchKernelGGL(k_topk2, dim3(B_), dim3(1024), 0, stream,
                       score1, idx1, keep1, sel_score, sel_cls, sel_orig,
                       boxes, cor2, 1);
    if (sb)
      hipLaunchKernelGGL(k_nms_build<true>, dim3(B_ * NB_), dim3(256), 0,
                         stream, cor2, m1b, m0b, mask2);
    else
      hipLaunchKernelGGL(k_nms_build<false>, dim3(B_ * NB_), dim3(256), 0,
                         stream, cor2, m1b, m0b, mask2);
    hipLaunchKernelGGL(k_nms_scan2, dim3(B_), dim3(1024), 0, stream,
                       mask2, sel_score, sel_cls, sel_orig, boxes, out);
  } else {
    hipLaunchKernelGGL(k_nms1, dim3(B_ * C_), dim3(1024), 0, stream,
                       boxes, score1, idx1, keep1);
    hipLaunchKernelGGL(k_topk2, dim3(B_), dim3(1024), 0, stream,
                       score1, idx1, keep1, sel_score, sel_cls, sel_orig,
                       boxes, cor2, 0);
    hipLaunchKernelGGL(k_nms2_out, dim3(B_), dim3(1024), 0, stream,
                       boxes, sel_score, sel_cls, sel_orig, out);
  }
}

// Round 6
// 214.840 us; speedup vs baseline: 3.3330x; 3.3330x over previous
//
#include <hip/hip_runtime.h>
#include <stdint.h>
#include <string.h>

typedef unsigned int u32;
typedef unsigned long long u64;

#define B_ 8
#define N_ 100000
#define C_ 10
#define K1_ 1000
#define N2_ (C_ * K1_)
#define NBIN 4096
#define CAP 4096       // fallback / topk2 sort capacity
#define CAP_C 2048     // fast-path candidate capacity per slice
#define SEGROWS 256    // fused-NMS segment rows (fallback path)
#define MIN_CONF_F 0.05f
#define NMS_IOU_F 0.4f
#define POST_IOU_F 0.65f
#define T0_F 0.985f    // conservative fast-path threshold (per-slice count ~1500)

#define TOTAL_F4 (B_ * N_ * C_ / 4)  // 2,000,000 float4s
#define CBLK 512                     // compact blocks
#define LCAP 512                     // per-block candidate capacity (lambda~234, 18 sigma)
#define HDRW 84                      // u32 stride per compact-block header

// split-NMS parameters (R2/R4 best-measured geometry)
#define NTILE 136   // upper-triangular 64x64 tiles of the 1024x1024 pair matrix
#define NB_ 34      // build blocks per slice (4 waves each -> 1 tile per wave)
#define TPB_ 4      // tiles per build block

static __device__ __forceinline__ u32 next_pow2_ge(u32 x, u32 lo, u32 hi) {
  u32 n = lo;
  while (n < x && n < hi) n <<= 1;
  return n;
}

// triangular tile id of (rt, w), w >= rt
#define TILE_ID(rt, w) ((rt) * 16 - (((rt) * ((rt) - 1)) >> 1) + ((w) - (rt)))

// Prep: one thread writes one corner record (bit-identical FP to the
// validated k_nms_prep body).
static __device__ __forceinline__ void prep_write(const float* __restrict__ bb,
                                                  float s, int oi,
                                                  float4* __restrict__ cor,
                                                  int pos) {
  bool v = (s >= MIN_CONF_F);
  float cx = 0.f, cy = 0.f, w = 0.f, h = 0.f;
  if (v) {
    const float4 bp = *(const float4*)(bb + (size_t)oi * 4);
    cx = bp.x; cy = bp.y; w = bp.z; h = bp.w;
  }
  float y1 = cy - h * 0.5f, x1 = cx - w * 0.5f;
  float y2 = cy + h * 0.5f, x2 = cx + w * 0.5f;
  cor[pos] = make_float4(y1, x1, y2, x2);
}

// Exact threshold predicate, all-f32 (double-float). Reproduces
// (double)inter OP M*(double)den where M = m1+m0 (25-bit midpoint, product
// exact in f64): t+e = m1*den exactly (TwoProdFMA), r = fl(e + m0*den) —
// single rounding preserves sign incl. exact ties; d = inter-t is exact in
// the decision region (Sterbenz). _rn intrinsics pin against fp-contract.
template <bool STRICT>
static __device__ __forceinline__ bool iou_pred(float inter, float den,
                                                float m1, float m0) {
  float t = __fmul_rn(m1, den);
  float e = __builtin_fmaf(m1, den, -t);
  float r = __builtin_fmaf(m0, den, e);
  float d = __fsub_rn(inter, t);
  return STRICT ? (d > r) : (d >= r);
}

// One 64x64 mask tile from LDS-resident corners/areas (validated R14 body).
template <bool STRICT>
static __device__ __forceinline__ void build_tile(const float4* __restrict__ box4,
                                                  const float* __restrict__ area,
                                                  int tt, int lane,
                                                  float m1, float m0,
                                                  u64* __restrict__ mg) {
  int rt = 0, bse = 0;
  while (tt >= bse + (16 - rt)) { bse += 16 - rt; ++rt; }
  const int w = rt + (tt - bse);
  const int row = (rt << 6) | lane;

  const float4 ib = box4[row];
  const float ia = area[row];
  const float4* jcol = &box4[w << 6];
  const float* jarea = &area[w << 6];
  u32 mhi = 0, mlo = 0;
#pragma unroll 8
  for (int j = 63; j >= 32; --j) {
    const float4 jb = jcol[j];
    const float ja = jarea[j];
    float ih = fminf(ib.z, jb.z) - fmaxf(ib.x, jb.x); ih = fmaxf(ih, 0.0f);
    float iw_ = fminf(ib.w, jb.w) - fmaxf(ib.y, jb.y); iw_ = fmaxf(iw_, 0.0f);
    float inter = ih * iw_;
    float den = fmaxf((ia + ja) - inter, 1e-8f);
    bool p_ = iou_pred<STRICT>(inter, den, m1, m0);
    mhi = (mhi << 1) | (p_ ? 1u : 0u);
  }
#pragma unroll 8
  for (int j = 31; j >= 0; --j) {
    const float4 jb = jcol[j];
    const float ja = jarea[j];
    float ih = fminf(ib.z, jb.z) - fmaxf(ib.x, jb.x); ih = fmaxf(ih, 0.0f);
    float iw_ = fminf(ib.w, jb.w) - fmaxf(ib.y, jb.y); iw_ = fmaxf(iw_, 0.0f);
    float inter = ih * iw_;
    float den = fmaxf((ia + ja) - inter, 1e-8f);
    bool p_ = iou_pred<STRICT>(inter, den, m1, m0);
    mlo = (mlo << 1) | (p_ ? 1u : 0u);
  }
  u64 m = ((u64)mhi << 32) | (u64)mlo;
  if (w == rt) m &= (lane == 63) ? 0ull : (~0ull << (lane + 1));
  mg[(tt << 6) + lane] = m;  // coalesced 512-B store
}

// ---------------------------------------------------------------------------
// Wave-synchronous bitonic sort (desc) for 1024 threads. Exchange pairs with
// j <= 64 stay inside a wave-owned, 128-element aligned block (proof: for
// t in [64w,64w+64), i = ((t&~(j-1))<<1)|(t&(j-1)) and l = i|j both lie in
// [128w, 128w+128) when j<=64; for n=4096 the t+1024 iteration owns block
// w+16 likewise). Wave64 LDS ops complete in order within a wave, so those
// steps need no barrier. Barrier only before a cross step (j>=128) and
// before the first step after a cross step.
// ---------------------------------------------------------------------------
__device__ __forceinline__ void bitonic_sort_desc_ws(u64* buf, u32 n, int tid) {
  bool prev_cross = true;  // initial fill was block-wide scattered -> barrier
  for (u32 kk = 2; kk <= n; kk <<= 1) {
    for (u32 j = kk >> 1; j > 0; j >>= 1) {
      const bool cross = (j >= 128);
      if (cross || prev_cross) __syncthreads();
      for (u32 t = (u32)tid; t < (n >> 1); t += 1024) {
        u32 i = ((t & ~(j - 1)) << 1) | (t & (j - 1));
        u32 l = i | j;
        u64 a = buf[i], bb = buf[l];
        bool desc = ((i & kk) == 0);
        if (desc ? (a < bb) : (a > bb)) { buf[i] = bb; buf[l] = a; }
      }
      prev_cross = cross;
    }
  }
  __syncthreads();  // publish: readers read outside their wave's block
}

// ---------------------------------------------------------------------------
// Pass 1 (LDS-staged compaction). No global atomics, no init kernel:
// each block writes its candidates grouped by slice into its own segment,
// plus a header hdr[bk][0..80] = exclusive per-slice prefix, hdr[bk][81] = ovf.
// Everything is freshly written every call (poison-proof). Validated R4 body.
// ---------------------------------------------------------------------------
__global__ __launch_bounds__(256) void k_compact(const float* __restrict__ cls,
                                                 u64* __restrict__ cand,
                                                 u32* __restrict__ hdr) {
  __shared__ u32 lcnt[B_ * C_];
  __shared__ u32 lpre[B_ * C_ + 1];
  __shared__ u32 ltot;
  __shared__ u32 lovf;
  __shared__ u64 ekey[LCAP];
  __shared__ u32 emeta[LCAP];  // (slice<<16) | local_rank

  const int tid = threadIdx.x;
  const u32 bk = blockIdx.x;
  if (tid < B_ * C_) lcnt[tid] = 0;
  if (tid == 0) { ltot = 0; lovf = 0; }
  __syncthreads();

  const u32 lo = bk * ((TOTAL_F4 + CBLK - 1) / CBLK);
  u32 hi = lo + ((TOTAL_F4 + CBLK - 1) / CBLK);
  if (hi > TOTAL_F4) hi = TOTAL_F4;

  const float4* p4 = (const float4*)cls;
  for (u32 f = lo + tid; f < hi; f += 256) {
    float4 v = p4[f];
    u32 e = f * 4u;
    float vs[4] = {v.x, v.y, v.z, v.w};
#pragma unroll
    for (int j = 0; j < 4; ++j) {
      float s = vs[j];
      if (s >= T0_F) {
        u32 g = e + (u32)j;           // flat index into (B,N,C)
        u32 gi = g / (u32)C_;         // b*N + i
        u32 c = g - gi * (u32)C_;
        u32 bi = gi / (u32)N_;
        u32 i = gi - bi * (u32)N_;
        u32 slice = bi * (u32)C_ + c;
        u32 rank = atomicAdd(&lcnt[slice], 1u);
        u32 pos = atomicAdd(&ltot, 1u);
        if (pos < LCAP) {
          ekey[pos] = ((u64)__float_as_uint(s) << 32) | (u32)(~i);
          emeta[pos] = (slice << 16) | rank;
        } else {
          lovf = 1;
        }
      }
    }
  }
  __syncthreads();

  // exclusive prefix of lcnt -> lpre[0..80] (Hillis-Steele, 7 steps)
  if (tid < B_ * C_) lpre[tid + 1] = lcnt[tid];
  if (tid == 0) lpre[0] = 0;
  __syncthreads();
  for (int off = 1; off < B_ * C_; off <<= 1) {
    u32 v = 0;
    const bool act = (tid >= off && tid <= B_ * C_);
    if (act) v = lpre[tid - off];
    __syncthreads();
    if (act) lpre[tid] += v;
    __syncthreads();
  }

  // scatter into slice-grouped segment
  u32 tot = ltot;
  if (tot > LCAP) tot = LCAP;
  u64* seg = cand + (size_t)bk * LCAP;
  for (u32 p = tid; p < tot; p += 256) {
    u32 mta = emeta[p];
    u32 slice = mta >> 16;
    u32 rank = mta & 0xFFFFu;
    u32 dst = lpre[slice] + rank;
    if (dst < LCAP) seg[dst] = ekey[p];  // garbage on ovf; sel ignores then
  }
  if (tid <= B_ * C_) hdr[bk * HDRW + tid] = lpre[tid];
  if (tid == 0) hdr[bk * HDRW + 81] = lovf;
}

// ---------------------------------------------------------------------------
// Pass 2: gather per-slice candidates, wave-sync bitonic sort, emit top 1000.
// Header combine is now register-resident: per-thread cnt/start, wave
// shuffle-scan for the exclusive prefix, 8 wave totals in LDS (2 barriers
// instead of 18). Exact histogram fallback inlined (original full-barrier
// sort, statistically dead); prep fused as epilogue.
// ---------------------------------------------------------------------------
__global__ __launch_bounds__(1024) void k_sel(const float* __restrict__ cls,
                                              const u64* __restrict__ cand,
                                              const u32* __restrict__ hdr,
                                              float* __restrict__ score1,
                                              int* __restrict__ idx1,
                                              const float* __restrict__ boxes,
                                              float4* __restrict__ cor1,
                                              int do_prep) {
  const int slice = blockIdx.x;
  const int tid = threadIdx.x;
  const int bd = 1024;
  const int lane = tid & 63, wv = tid >> 6;

  __shared__ u32 hist[NBIN];  // fallback histogram only
  __shared__ u64 buf[CAP];
  __shared__ u32 wsum[8];
  __shared__ int sh_b1;
  __shared__ u32 sh_base, sh_T, sh_cnt, sh_ovf;

  if (tid == 0) sh_ovf = 0;
  __syncthreads();

  u32 mycnt = 0, mystart = 0, incl = 0;
  if (tid < CBLK) {
    const u32* h = hdr + (size_t)tid * HDRW;
    u32 a = h[slice], b2 = h[slice + 1];
    mystart = a;
    mycnt = b2 - a;
    if (h[81]) sh_ovf = 1;
    // wave-inclusive scan of mycnt (waves 0..7, shuffle, barrier-free)
    incl = mycnt;
    for (int off = 1; off < 64; off <<= 1) {
      u32 v = (u32)__shfl_up((int)incl, off, 64);
      if (lane >= off) incl += v;
    }
    if (lane == 63) wsum[wv] = incl;
  }
  __syncthreads();

  u32 wbase = 0, m = 0;
#pragma unroll
  for (int w2 = 0; w2 < 8; ++w2) {
    u32 v = wsum[w2];
    if (w2 < wv) wbase += v;
    m += v;
  }
  const bool fast = (sh_ovf == 0) && m >= (u32)K1_ && m <= (u32)CAP_C;

  if (fast) {
    if (tid < CBLK) {
      u32 base = wbase + incl - mycnt;  // exclusive prefix
      const u64* src = cand + (size_t)tid * LCAP + mystart;
      for (u32 r = 0; r < mycnt; ++r) buf[base + r] = src[r];
    }
    const u32 nn = next_pow2_ge(m, 1024u, (u32)CAP_C);
    for (u32 i2 = (u32)tid; i2 < nn; i2 += bd)
      if (i2 >= m) buf[i2] = 0ull;  // disjoint from gather region: no barrier
    bitonic_sort_desc_ws(buf, nn, tid);  // opens with barrier, ends with one

    float os = -1.0f; int ooi = 0;
    if (tid < K1_) {
      u64 e = buf[tid];
      u32 k = (u32)(e >> 32);
      os = __uint_as_float(k);     // fast path: k != 0 always (s >= T0)
      ooi = (int)(~(u32)e);
      score1[slice * K1_ + tid] = os;
      idx1[slice * K1_ + tid] = ooi;
    }
    if (do_prep)
      prep_write(boxes + (size_t)(slice / C_) * N_ * 4, os, ooi, cor1,
                 (slice << 10) + tid);
    return;
  }

  // ---- exact fallback: two-level histogram select over the full column ----
  const int b = slice / C_, c = slice % C_;

  for (int i = tid; i < NBIN; i += bd) hist[i] = 0;
  __syncthreads();
  for (int i = tid; i < N_; i += bd) {
    float s = cls[((size_t)b * N_ + i) * C_ + c];
    if (s >= MIN_CONF_F) atomicAdd(&hist[__float_as_uint(s) >> 19], 1u);
  }
  __syncthreads();
  if (tid == 0) {
    u32 cum = 0; int b1 = -1; u32 base = 0;
    for (int bin = NBIN - 1; bin >= 0; --bin) {
      cum += hist[bin];
      if (cum >= (u32)K1_) { b1 = bin; base = cum - hist[bin]; break; }
    }
    sh_b1 = b1; sh_base = base;
    if (b1 < 0) sh_T = 0;
  }
  __syncthreads();
  const int b1 = sh_b1;

  if (b1 >= 0) {
    const u32 base = sh_base;
    for (int i = tid; i < NBIN; i += bd) hist[i] = 0;
    __syncthreads();
    for (int i = tid; i < N_; i += bd) {
      float s = cls[((size_t)b * N_ + i) * C_ + c];
      if (s >= MIN_CONF_F) {
        u32 k = __float_as_uint(s);
        if ((int)(k >> 19) == b1) atomicAdd(&hist[(k >> 7) & 0xFFFu], 1u);
      }
    }
    __syncthreads();
    if (tid == 0) {
      u32 cum = base;
      u32 T = ((u32)b1) << 19;
      for (int bin = NBIN - 1; bin >= 0; --bin) {
        cum += hist[bin];
        if (cum >= (u32)K1_) { T = (((u32)b1) << 19) | (((u32)bin) << 7); break; }
      }
      sh_T = T;
    }
    __syncthreads();
  }

  if (tid == 0) sh_cnt = 0;
  __syncthreads();
  const u32 T = sh_T;
  for (int i = tid; i < N_; i += bd) {
    float s = cls[((size_t)b * N_ + i) * C_ + c];
    if (s >= MIN_CONF_F) {
      u32 k = __float_as_uint(s);
      if (k >= T) {
        u32 pos = atomicAdd(&sh_cnt, 1u);
        if (pos < CAP) buf[pos] = ((u64)k << 32) | (u32)(~(u32)i);
      }
    }
  }
  __syncthreads();
  u32 mm = sh_cnt; if (mm > CAP) mm = CAP;
  for (int i = tid; i < CAP; i += bd)
    if ((u32)i >= mm) buf[i] = 0ull;
  __syncthreads();

  // original full-barrier sort (kept verbatim in the dead-cold fallback)
  for (u32 kk = 2; kk <= CAP; kk <<= 1) {
    for (u32 j = kk >> 1; j > 0; j >>= 1) {
      for (u32 i = tid; i < CAP; i += bd) {
        u32 l = i ^ j;
        if (l > i) {
          u64 a = buf[i], bb2 = buf[l];
          bool desc = ((i & kk) == 0);
          if (desc ? (a < bb2) : (a > bb2)) { buf[i] = bb2; buf[l] = a; }
        }
      }
      __syncthreads();
    }
  }

  float os = -1.0f; int ooi = 0;
  if (tid < K1_) {
    u64 e = buf[tid];
    u32 k = (u32)(e >> 32);
    if (k != 0) { os = __uint_as_float(k); ooi = (int)(~(u32)e); }
    score1[slice * K1_ + tid] = os;
    idx1[slice * K1_ + tid] = ooi;
  }
  if (do_prep)
    prep_write(boxes + (size_t)(slice / C_) * N_ * 4, os, ooi, cor1,
               (slice << 10) + tid);
}

// ===========================================================================
// Split NMS: build (parallel across CUs) -> hierarchical scan. R4 verbatim.
// ===========================================================================
template <bool STRICT>
__global__ __launch_bounds__(256) void k_nms_build(const float4* __restrict__ cor,
                                                   float m1, float m0,
                                                   u64* __restrict__ maskg) {
  __shared__ float4 box4[1024];
  __shared__ float area[1024];
  const int blk = blockIdx.x;
  const int slice = blk / NB_;
  const int sub = blk - slice * NB_;
  const int tid = threadIdx.x, wave = tid >> 6, lane = tid & 63;

  for (int p = tid; p < 1024; p += 256) {
    const float4 c = cor[(slice << 10) + p];
    box4[p] = c;
    area[p] = (c.z - c.x) * (c.w - c.y);
  }
  __syncthreads();

  u64* mg = maskg + (size_t)slice * (NTILE * 64);

  for (int k = wave; k < TPB_; k += 4) {
    const int tt = sub * TPB_ + k;
    if (tt >= NTILE) break;
    build_tile<STRICT>(box4, area, tt, lane, m1, m0, mg);
  }
}

// Hierarchical scan core (rolled, O(1) registers). Exact greedy keep set.
__device__ void scan_core(const u64* __restrict__ mg, float s,
                          u64* __restrict__ keepb) {
  const int tid = threadIdx.x, wv = tid >> 6, lane = tid & 63;
  const u64 myvalid = __ballot(s >= MIN_CONF_F);

  u64 ext_partial = 0;

#pragma unroll 1
  for (int g = 0; g < 16; ++g) {
    u64 Tg = 0ull;
    if (g <= wv) Tg = mg[(TILE_ID(g, wv) << 6) + lane];
    const u64 nz = __ballot(Tg != 0ull);  // suppressor rows in this tile
    if (wv == g) {
      u64 ext = ext_partial;
      for (int off = 1; off < 64; off <<= 1) {
        u32 lo = (u32)__shfl_xor((int)(u32)ext, off, 64);
        u32 hi = (u32)__shfl_xor((int)(u32)(ext >> 32), off, 64);
        ext |= ((u64)hi << 32) | lo;
      }
      const u32 tlo = (u32)Tg, thi = (u32)(Tg >> 32);
      u64 rem = myvalid & ~ext;
      u64 cand = rem & nz;
      while (cand) {
        int i = __ffsll((long long)cand) - 1;
        cand &= cand - 1;  // clear bit i
        if ((rem >> i) & 1ull) {
          u32 rlo = __builtin_amdgcn_readlane(tlo, i);
          u32 rhi = __builtin_amdgcn_readlane(thi, i);
          u64 row = ((u64)rhi << 32) | rlo;  // bits only > i (diag-masked)
          rem &= ~row;
          cand &= ~row;
        }
      }
      if (lane == 0) keepb[g] = rem;
    }
    __syncthreads();
    if (wv > g) {
      u64 kg = keepb[g];  // broadcast LDS read
      if ((kg >> lane) & 1ull) ext_partial |= Tg;
    }
  }
}

__global__ __launch_bounds__(1024) void k_nms_scan1(const u64* __restrict__ maskg,
                                                    const float* __restrict__ score1,
                                                    int* __restrict__ keep1) {
  __shared__ u64 keepb[16];
  const int slice = blockIdx.x;
  const int tid = threadIdx.x;
  float s = (tid < K1_) ? score1[slice * K1_ + tid] : -1.0f;
  scan_core(maskg + (size_t)slice * (NTILE * 64), s, keepb);
  __syncthreads();
  if (tid < K1_)
    keep1[slice * K1_ + tid] = (int)((keepb[tid >> 6] >> (tid & 63)) & 1ull);
}

__global__ __launch_bounds__(1024) void k_nms_scan2(const u64* __restrict__ maskg,
                                                    const float* __restrict__ sel_score,
                                                    const int* __restrict__ sel_cls,
                                                    const int* __restrict__ sel_orig,
                                                    const float* __restrict__ boxes,
                                                    float* __restrict__ out) {
  __shared__ u64 keepb[16];
  __shared__ short ord[K1_];
  __shared__ int lbase[17];
  __shared__ int ordc;
  const int b = blockIdx.x;
  const int tid = threadIdx.x;
  float s = (tid < K1_) ? sel_score[b * K1_ + tid] : -1.0f;
  scan_core(maskg + (size_t)b * (NTILE * 64), s, keepb);
  __syncthreads();

  if (tid == 0) {
    int acc = 0;
    for (int wdx = 0; wdx < 16; ++wdx) {
      lbase[wdx] = acc;
      acc += __popcll(keepb[wdx]);
    }
    lbase[16] = acc;
    ordc = acc;
  }
  __syncthreads();
  if (tid < 16) {
    u64 m = keepb[tid];
    int base = lbase[tid];
    while (m) {
      int bit = __ffsll((long long)m) - 1;
      ord[base++] = (short)((tid << 6) | bit);
      m &= m - 1;
    }
  }
  __syncthreads();

  for (int t = tid; t < K1_ * 6; t += 1024) out[(size_t)b * K1_ * 6 + t] = 0.0f;
  __syncthreads();

  const int cnt = ordc;
  for (int q = tid; q < cnt; q += 1024) {
    int p = ord[q];
    int oi = sel_orig[b * K1_ + p];
    const float4 bp = *(const float4*)(boxes + ((size_t)b * N_ + oi) * 4);
    float* o = out + ((size_t)b * K1_ + q) * 6;
    o[0] = bp.x; o[1] = bp.y; o[2] = bp.z; o[3] = bp.w;
    o[4] = (float)sel_cls[b * K1_ + p];
    o[5] = sel_score[b * K1_ + p];
  }
}

// ---------------------------------------------------------------------------
// Parallel boundary-bin select over a 4096-bin LDS histogram (1024 threads).
// Wave-shuffle suffix scan + 16 wave totals (2 barriers, was 20). Per-thread
// results identical to the original aux[]-based version: aux[t] = suf + upw,
// up = aux[t+1] = suf - own + upw (holds at wave edges since suf==own at
// lane 63, and aux[1024] == 0).
// ---------------------------------------------------------------------------
__device__ __forceinline__ void suffix_select(const u32* __restrict__ hist,
                                              u32* __restrict__ wtot,  // [16]
                                              u32 base, u32 K,
                                              int* out_bin, u32* out_next) {
  const int t = threadIdx.x;  // 1024
  const int lane = t & 63, wv = t >> 6;
  u32 h0 = hist[4 * t], h1 = hist[4 * t + 1];
  u32 h2 = hist[4 * t + 2], h3 = hist[4 * t + 3];
  const u32 own = h0 + h1 + h2 + h3;
  u32 suf = own;
  for (int off = 1; off < 64; off <<= 1) {
    u32 v = (u32)__shfl_down((int)suf, off, 64);
    if (lane + off < 64) suf += v;
  }
  if (lane == 0) wtot[wv] = suf;
  __syncthreads();
  u32 upw = 0;
#pragma unroll
  for (int w2 = 0; w2 < 16; ++w2) {
    u32 v = wtot[w2];
    if (w2 > wv) upw += v;
  }
  if (t == 0 && base + (suf + upw) < K) { *out_bin = -1; *out_next = base; }
  u32 up = suf - own + upw;  // = aux[t+1]
  u32 s3 = h3 + up;
  u32 s2 = h2 + s3;
  u32 s1 = h1 + s2;
  u32 s0 = h0 + s1;
  u32 c0 = base + s0, c1 = base + s1, c2 = base + s2, c3 = base + s3;
  u32 c4 = base + up;
  if (c0 >= K && c1 < K) { *out_bin = 4 * t;     *out_next = c1; }
  if (c1 >= K && c2 < K) { *out_bin = 4 * t + 1; *out_next = c2; }
  if (c2 >= K && c3 < K) { *out_bin = 4 * t + 2; *out_next = c3; }
  if (c3 >= K && c4 < K) { *out_bin = 4 * t + 3; *out_next = c4; }
  __syncthreads();
}

// ---------------------------------------------------------------------------
// Kernel 3: per-batch top-1000 over the C*K1 survivors (stable, flat-index
// tie-break). Prep for pass-2 NMS fused as an epilogue.
// ---------------------------------------------------------------------------
__global__ __launch_bounds__(1024) void k_topk2(const float* __restrict__ score1,
                                                const int* __restrict__ idx1,
                                                const int* __restrict__ keep1,
                                                float* __restrict__ sel_score,
                                                int* __restrict__ sel_cls,
                                                int* __restrict__ sel_orig,
                                                const float* __restrict__ boxes,
                                                float4* __restrict__ cor2,
                                                int do_prep) {
  const int b = blockIdx.x;
  const int tid = threadIdx.x;

  __shared__ u32 hist[NBIN];
  __shared__ u32 wtot[16];
  __shared__ u64 buf[CAP];
  __shared__ int sh_bin;
  __shared__ u32 sh_next;
  __shared__ u32 sh_T, sh_cnt;

  for (int i = tid; i < NBIN; i += 1024) hist[i] = 0;
  __syncthreads();
  for (int f = tid; f < N2_; f += 1024) {
    if (keep1[b * N2_ + f])
      atomicAdd(&hist[__float_as_uint(score1[b * N2_ + f]) >> 19], 1u);
  }
  __syncthreads();
  suffix_select(hist, wtot, 0u, (u32)K1_, &sh_bin, &sh_next);
  const int b1 = sh_bin;
  const u32 base = sh_next;

  if (b1 >= 0) {
    for (int i = tid; i < NBIN; i += 1024) hist[i] = 0;
    if (tid == 0) sh_bin = -2;
    __syncthreads();
    for (int f = tid; f < N2_; f += 1024) {
      if (keep1[b * N2_ + f]) {
        u32 k = __float_as_uint(score1[b * N2_ + f]);
        if ((int)(k >> 19) == b1) atomicAdd(&hist[(k >> 7) & 0xFFFu], 1u);
      }
    }
    __syncthreads();
    suffix_select(hist, wtot, base, (u32)K1_, &sh_bin, &sh_next);
    if (tid == 0) {
      int b2 = sh_bin;
      sh_T = (b2 >= 0) ? ((((u32)b1) << 19) | (((u32)b2) << 7))
                       : (((u32)b1) << 19);
    }
  } else {
    if (tid == 0) sh_T = 0;
  }
  if (tid == 0) sh_cnt = 0;
  __syncthreads();

  const u32 T = sh_T;
  for (int f = tid; f < N2_; f += 1024) {
    if (keep1[b * N2_ + f]) {
      u32 k = __float_as_uint(score1[b * N2_ + f]);
      if (k >= T) {
        u32 pos = atomicAdd(&sh_cnt, 1u);
        if (pos < CAP) buf[pos] = ((u64)k << 32) | (u32)(~(u32)f);
      }
    }
  }
  __syncthreads();
  u32 m = sh_cnt; if (m > CAP) m = CAP;
  const u32 n = next_pow2_ge(m, 1024u, (u32)CAP);
  for (u32 i = tid; i < n; i += 1024)
    if (i >= m) buf[i] = 0ull;
  bitonic_sort_desc_ws(buf, n, tid);  // opens and closes with barriers

  float os = -1.0f; int ooi = 0;
  if (tid < K1_) {
    u64 e = buf[tid];
    u32 k = (u32)(e >> 32);
    float s; int cls, orig;
    if (k == 0) { s = -1.0f; cls = 0; orig = 0; }
    else {
      s = __uint_as_float(k);
      u32 f = ~(u32)e;
      cls = (int)(f / K1_);
      int slot = (int)(f - (u32)cls * K1_);
      orig = idx1[(b * C_ + cls) * K1_ + slot];
    }
    sel_score[b * K1_ + tid] = s;
    sel_cls[b * K1_ + tid] = cls;
    sel_orig[b * K1_ + tid] = orig;
    os = s; ooi = orig;
  }
  if (do_prep)
    prep_write(boxes + (size_t)b * N_ * 4, os, ooi, cor2, (b << 10) + tid);
}

// ===========================================================================
// Fused NMS (fallback when ws is too small) — validated R8 code, verbatim.
// ===========================================================================
__device__ __forceinline__ void nms_run(const float* __restrict__ scores,
                                        const int* __restrict__ origs,
                                        const float* __restrict__ boxesB,
                                        float thr,
                                        float4* box4, float* area,
                                        u64* mask, u64* validw, u64* keepw) {
  const int tid = threadIdx.x;
  const int wave = tid >> 6, lane = tid & 63;

  {
    const int p = tid;
    float s = (p < K1_) ? scores[p] : -1.0f;
    bool v = (s >= MIN_CONF_F);
    float cx = 0.f, cy = 0.f, w = 0.f, h = 0.f;
    if (v) {
      const float4 bp = *(const float4*)(boxesB + (size_t)origs[p] * 4);
      cx = bp.x; cy = bp.y; w = bp.z; h = bp.w;
    }
    float y1 = cy - h * 0.5f, x1 = cx - w * 0.5f;
    float y2 = cy + h * 0.5f, x2 = cx + w * 0.5f;
    box4[p] = make_float4(y1, x1, y2, x2);
    area[p] = (y2 - y1) * (x2 - x1);
    u64 mb = __ballot(v);
    if (lane == 0) validw[wave] = mb;
  }
  __syncthreads();

  const float cf = thr;
  const float cnext = __uint_as_float(__float_as_uint(cf) + 1u);
  const double M = ((double)cf + (double)cnext) * 0.5;
  const bool strict = ((__float_as_uint(cf) & 1u) == 0u);

  const int ss = wave & 3, qq = wave >> 2;
  int col;
  if (qq == 0) col = ss;
  else if (qq == 1) col = 7 - ss;
  else if (qq == 2) col = 8 + ss;
  else col = 15 - ss;

  u64 vw = validw[tid & 15];
  u64 supp = 0;

  for (int seg = 0; seg < 4; ++seg) {
    const int ibase = seg * SEGROWS;
    const int lim = (K1_ - ibase < SEGROWS) ? (K1_ - ibase) : SEGROWS;
    const int rtg0 = ibase >> 6;
    int ntile = col - rtg0 + 1;
    if (ntile < 0) ntile = 0;
    if (ntile > 4) ntile = 4;

    if (ntile > 0) {
      float4 ib[4];
      float ia[4];
#pragma unroll
      for (int r = 0; r < 4; ++r) {
        if (r < ntile) {
          const int i = ibase + (r << 6) + lane;
          ib[r] = box4[i];
          ia[r] = area[i];
        }
      }
      u32 mhi[4] = {0, 0, 0, 0}, mlo[4] = {0, 0, 0, 0};
      const float4* jcol = &box4[col << 6];

      for (int j = 63; j >= 32; --j) {
        const float4 jb = jcol[j];
        const float ja = (jb.z - jb.x) * (jb.w - jb.y);
#pragma unroll
        for (int r = 0; r < 4; ++r) {
          if (r < ntile) {
            float ih = fminf(ib[r].z, jb.z) - fmaxf(ib[r].x, jb.x);
            ih = fmaxf(ih, 0.0f);
            float iw_ = fminf(ib[r].w, jb.w) - fmaxf(ib[r].y, jb.y);
            iw_ = fmaxf(iw_, 0.0f);
            float inter = ih * iw_;
            float den = fmaxf((ia[r] + ja) - inter, 1e-8f);
            bool p_ = strict ? ((double)inter > M * (double)den)
                             : ((double)inter >= M * (double)den);
            mhi[r] = (mhi[r] << 1) | (p_ ? 1u : 0u);
          }
        }
      }
      for (int j = 31; j >= 0; --j) {
        const float4 jb = jcol[j];
        const float ja = (jb.z - jb.x) * (jb.w - jb.y);
#pragma unroll
        for (int r = 0; r < 4; ++r) {
          if (r < ntile) {
            float ih = fminf(ib[r].z, jb.z) - fmaxf(ib[r].x, jb.x);
            ih = fmaxf(ih, 0.0f);
            float iw_ = fminf(ib[r].w, jb.w) - fmaxf(ib[r].y, jb.y);
            iw_ = fmaxf(iw_, 0.0f);
            float inter = ih * iw_;
            float den = fmaxf((ia[r] + ja) - inter, 1e-8f);
            bool p_ = strict ? ((double)inter > M * (double)den)
                             : ((double)inter >= M * (double)den);
            mlo[r] = (mlo[r] << 1) | (p_ ? 1u : 0u);
          }
        }
      }
#pragma unroll
      for (int r = 0; r < 4; ++r) {
        if (r < ntile) {
          u64 m = ((u64)mhi[r] << 32) | (u64)mlo[r];
          if (rtg0 + r == col)
            m &= (lane == 63) ? 0ull : (~0ull << (lane + 1));
          const int il = (r << 6) | lane;
          mask[il * 16 + (col ^ (il & 15))] = m;
        }
      }
    }
    __syncthreads();

    if (tid < 64) {
      const int l = tid & 15;
      u64 r0 = 0, r1 = 0, r2 = 0, r3 = 0;
      if (l >= ((ibase + 0) >> 6)) r0 = mask[0 * 16 + (l ^ 0)];
      if (l >= ((ibase + 1) >> 6)) r1 = mask[1 * 16 + (l ^ 1)];
      if (l >= ((ibase + 2) >> 6)) r2 = mask[2 * 16 + (l ^ 2)];
      if (l >= ((ibase + 3) >> 6)) r3 = mask[3 * 16 + (l ^ 3)];
      for (int il = 0; il < lim; il += 4) {
        const int i0 = ibase + il;
        const int n0 = (il + 4 < lim) ? il + 4 : il;
        const int n1 = (il + 5 < lim) ? il + 5 : il;
        const int n2 = (il + 6 < lim) ? il + 6 : il;
        const int n3 = (il + 7 < lim) ? il + 7 : il;
        u64 m0 = r0, m1 = r1, m2 = r2, m3 = r3;
        r0 = (l >= ((ibase + n0) >> 6)) ? mask[n0 * 16 + (l ^ (n0 & 15))] : 0ull;
        r1 = (l >= ((ibase + n1) >> 6)) ? mask[n1 * 16 + (l ^ (n1 & 15))] : 0ull;
        r2 = (l >= ((ibase + n2) >> 6)) ? mask[n2 * 16 + (l ^ (n2 & 15))] : 0ull;
        r3 = (l >= ((ibase + n3) >> 6)) ? mask[n3 * 16 + (l ^ (n3 & 15))] : 0ull;
        bool a;
        a = (tid == (i0 >> 6)) && (((vw & ~supp) >> (i0 & 63)) & 1ull);
        if (__any(a)) supp |= m0;
        a = (tid == ((i0 + 1) >> 6)) && (((vw & ~supp) >> ((i0 + 1) & 63)) & 1ull);
        if (__any(a)) supp |= m1;
        a = (tid == ((i0 + 2) >> 6)) && (((vw & ~supp) >> ((i0 + 2) & 63)) & 1ull);
        if (__any(a)) supp |= m2;
        a = (tid == ((i0 + 3) >> 6)) && (((vw & ~supp) >> ((i0 + 3) & 63)) & 1ull);
        if (__any(a)) supp |= m3;
      }
    }
    __syncthreads();
  }

  if (tid < 16) keepw[tid] = vw & ~supp;
}

__global__ __launch_bounds__(1024) void k_nms1(const float* __restrict__ boxes,
                                               const float* __restrict__ score1,
                                               const int* __restrict__ idx1,
                                               int* __restrict__ keep1) {
  __shared__ float4 box4[1024];
  __shared__ float area[1024];
  __shared__ u64 mask[SEGROWS * 16];
  __shared__ u64 validw[16], keepw[16];

  const int slice = blockIdx.x;
  const int b = slice / C_;
  nms_run(score1 + slice * K1_, idx1 + slice * K1_,
          boxes + (size_t)b * N_ * 4, NMS_IOU_F,
          box4, area, mask, validw, keepw);
  __syncthreads();

  const int p = threadIdx.x;
  if (p < K1_)
    keep1[slice * K1_ + p] = (int)((keepw[p >> 6] >> (p & 63)) & 1ull);
}

__global__ __launch_bounds__(1024) void k_nms2_out(const float* __restrict__ boxes,
                                                   const float* __restrict__ sel_score,
                                                   const int* __restrict__ sel_cls,
                                                   const int* __restrict__ sel_orig,
                                                   float* __restrict__ out) {
  __shared__ float4 box4[1024];
  __shared__ float area[1024];
  __shared__ u64 mask[SEGROWS * 16];
  __shared__ u64 validw[16], keepw[16];
  __shared__ short ord[K1_];
  __shared__ int lbase[17];
  __shared__ int ordc;

  const int b = blockIdx.x;
  const int tid = threadIdx.x;
  nms_run(sel_score + b * K1_, sel_orig + b * K1_,
          boxes + (size_t)b * N_ * 4, POST_IOU_F,
          box4, area, mask, validw, keepw);
  __syncthreads();

  if (tid == 0) {
    int acc = 0;
    for (int wdx = 0; wdx < 16; ++wdx) {
      lbase[wdx] = acc;
      acc += __popcll(keepw[wdx]);
    }
    lbase[16] = acc;
    ordc = acc;
  }
  __syncthreads();
  if (tid < 16) {
    u64 m = keepw[tid];
    int base = lbase[tid];
    while (m) {
      int bit = __ffsll((long long)m) - 1;
      ord[base++] = (short)((tid << 6) | bit);
      m &= m - 1;
    }
  }
  __syncthreads();

  for (int t = tid; t < K1_ * 6; t += 1024) out[(size_t)b * K1_ * 6 + t] = 0.0f;
  __syncthreads();

  const int cnt = ordc;
  for (int q = tid; q < cnt; q += 1024) {
    int p = ord[q];
    int oi = sel_orig[b * K1_ + p];
    const float4 bp = *(const float4*)(boxes + ((size_t)b * N_ + oi) * 4);
    float* o = out + ((size_t)b * K1_ + q) * 6;
    o[0] = bp.x; o[1] = bp.y; o[2] = bp.z; o[3] = bp.w;
    o[4] = (float)sel_cls[b * K1_ + p];
    o[5] = sel_score[b * K1_ + p];
  }
}

// ---------------------------------------------------------------------------
static inline void m_split(float cf, float* m1, float* m0, bool* strict) {
  u32 b; memcpy(&b, &cf, 4);
  u32 nb = b + 1; float cn; memcpy(&cn, &nb, 4);
  double M = ((double)cf + (double)cn) * 0.5;
  *m1 = (float)M;
  *m0 = (float)(M - (double)*m1);
  *strict = ((b & 1u) == 0u);
}

extern "C" void kernel_launch(void* const* d_in, const int* in_sizes, int n_in,
                              void* d_out, int out_size, void* d_ws, size_t ws_size,
                              hipStream_t stream) {
  const float* cls = (const float*)d_in[0];    // (8,100000,10) f32
  const float* boxes = (const float*)d_in[1];  // (8,100000,4)  f32
  float* out = (float*)d_out;                  // (8,1000,6)    f32

  char* ws = (char*)d_ws;
  float* score1    = (float*)(ws);                     // 80000 f32
  int*   idx1      = (int*)(ws + 320000);              // 80000 i32
  int*   keep1     = (int*)(ws + 640000);              // 80000 i32
  float* sel_score = (float*)(ws + 960000);            // 8000 f32
  int*   sel_cls   = (int*)(ws + 992000);              // 8000 i32
  int*   sel_orig  = (int*)(ws + 1024000);             // 8000 i32
  u32*   hdr       = (u32*)(ws + 1056000);             // 512*84 u32   -> 1228032
  u64*   cand      = (u64*)(ws + 1228032);             // 512*512 u64  -> 3325184
  u64*   mask1     = (u64*)(ws + 3325184);             // 80*8704 u64  -> 8895744
  u64*   mask2     = (u64*)(ws + 3325184);             // aliases mask1 (dead before reuse)
  float4* cor1     = (float4*)(ws + 8895744);          // 80*1024 f4   -> 10206464
  float4* cor2     = (float4*)(ws + 8895744);          // aliases cor1 (dead before reuse)
  const size_t WS_NEED = 10206464;

  const int do_fast = (ws_size >= WS_NEED) ? 1 : 0;

  float m1a, m0a, m1b, m0b; bool sa, sb;
  m_split(NMS_IOU_F, &m1a, &m0a, &sa);   // 0.4f  -> strict = false
  m_split(POST_IOU_F, &m1b, &m0b, &sb);  // 0.65f -> strict = true

  hipLaunchKernelGGL(k_compact, dim3(CBLK), dim3(256), 0, stream,
                     cls, cand, hdr);
  hipLaunchKernelGGL(k_sel, dim3(B_ * C_), dim3(1024), 0, stream,
                     cls, cand, hdr, score1, idx1, boxes, cor1, do_fast);

  if (do_fast) {
    if (sa)
      hipLaunchKernelGGL(k_nms_build<true>, dim3(B_ * C_ * NB_), dim3(256), 0,
                         stream, cor1, m1a, m0a, mask1);
    else
      hipLaunchKernelGGL(k_nms_build<false>, dim3(B_ * C_ * NB_), dim3(256), 0,
                         stream, cor1, m1a, m0a, mask1);
    hipLaunchKernelGGL(k_nms_scan1, dim3(B_ * C_), dim3(1024), 0, stream,
                       mask1, score1, keep1);
    hipLaunchKernelGGL(k_topk2, dim3(B_), dim3(1024), 0, stream,
                       score1, idx1, keep1, sel_score, sel_cls, sel_orig,
                       boxes, cor2, 1);
    if (sb)
      hipLaunchKernelGGL(k_nms_build<true>, dim3(B_ * NB_), dim3(256), 0,
                         stream, cor2, m1b, m0b, mask2);
    else
      hipLaunchKernelGGL(k_nms_build<false>, dim3(B_ * NB_), dim3(256), 0,
                         stream, cor2, m1b, m0b, mask2);
    hipLaunchKernelGGL(k_nms_scan2, dim3(B_), dim3(1024), 0, stream,
                       mask2, sel_score, sel_cls, sel_orig, boxes, out);
  } else {
    hipLaunchKernelGGL(k_nms1, dim3(B_ * C_), dim3(1024), 0, stream,
                       boxes, score1, idx1, keep1);
    hipLaunchKernelGGL(k_topk2, dim3(B_), dim3(1024), 0, stream,
                       score1, idx1, keep1, sel_score, sel_cls, sel_orig,
                       boxes, cor2, 0);
    hipLaunchKernelGGL(k_nms2_out, dim3(B_), dim3(1024), 0, stream,
                       boxes, sel_score, sel_cls, sel_orig, out);
  }
}